// Round 4
// baseline (176.772 us; speedup 1.0000x reference)
//
#include <hip/hip_runtime.h>
#include <hip/hip_bf16.h>
#include <math.h>

#define SELU_SCALE 1.0507009873554805f
#define SELU_ALPHA 1.6732632423543772f

static constexpr int B_ = 16, T_ = 16, L_ = 512, H_ = 768;
static constexpr int WSZ = 768 * 768;          // one weight matrix, elements
static constexpr int HNELEM = B_ * L_ * H_;    // 6291456
static constexpr int DJELEM = B_ * T_ * H_;    // 196608
// combined bf16 staging buffer layout: [hn | W1 | W2 | dj-gather]
static constexpr int ALLELEM = HNELEM + 2 * WSZ + DJELEM;   // 7667712 (/8/256 = 3744)

typedef __bf16 bf16x8 __attribute__((ext_vector_type(8)));
typedef float  f32x4  __attribute__((ext_vector_type(4)));

__device__ __forceinline__ float bf_lo(unsigned u) { return __uint_as_float(u << 16); }
__device__ __forceinline__ float bf_hi(unsigned u) { return __uint_as_float(u & 0xFFFF0000u); }

__device__ __forceinline__ float selu_core(float x) {
    float e = fmaf(__expf(x), SELU_ALPHA, -SELU_ALPHA);
    return x > 0.0f ? x : e;
}

__device__ __forceinline__ bf16x8 pack8(float4 a, float4 b) {
    bf16x8 o;
    o[0] = (__bf16)a.x; o[1] = (__bf16)a.y; o[2] = (__bf16)a.z; o[3] = (__bf16)a.w;
    o[4] = (__bf16)b.x; o[5] = (__bf16)b.y; o[6] = (__bf16)b.z; o[7] = (__bf16)b.w;
    return o;
}

// ---------------- prep: {hn, W1, W2, dec-gather} -> bf16 (one pass, ~7us) -------
// r3 post-mortem: gemm_k was 43.9us at MfmaUtil 7.9% -- the barrier-synced LDS
// staging serializes at ~1 wave/SIMD occupancy. Converting ALL gemm operands to
// bf16 up front lets gemm load MFMA fragments directly from global (16B/lane,
// r3-verified pattern) with zero LDS and zero barriers. ~40MB moved at HBM BW.
// Same RTN rounding as the old pack8 staging path -> bit-identical results.
// Also zeroes the loss accumulator.
__global__ __launch_bounds__(256) void prep_k(
        const float* __restrict__ hn, const float* __restrict__ dec,
        const float* __restrict__ w1, const float* __restrict__ w2,
        const int* __restrict__ Yi,
        __bf16* __restrict__ allb, float* __restrict__ out) {
    if (blockIdx.x == 0 && threadIdx.x == 0) out[0] = 0.0f;
    int idx = (blockIdx.x * 256 + threadIdx.x) * 8;
    const float* src;
    if (idx < HNELEM) {
        src = hn + idx;
    } else if (idx < HNELEM + WSZ) {
        src = w1 + (idx - HNELEM);
    } else if (idx < HNELEM + 2 * WSZ) {
        src = w2 + (idx - HNELEM - WSZ);
    } else {
        int e = idx - (HNELEM + 2 * WSZ);      // < 196608
        int r = e / 768, c = e - r * 768;      // r = bt, 8 elems stay in-row
        src = dec + ((size_t)((r >> 4) * L_ + Yi[r])) * H_ + c;
    }
    float4 a = *(const float4*)src;
    float4 b = *(const float4*)(src + 4);
    *(bf16x8*)(allb + idx) = pack8(a, b);
}

// ---------------- fused NT GEMM (WE + WD): no LDS, no barriers ------------------
// C[m][n] = sum_k A[m][k]*B[n][k], all operands pre-converted bf16. Each wave
// owns a 64x64 output tile (4x4 MFMA 16x16x32) and is fully independent: MFMA
// fragments load straight from global (lane -> row base + 16B at k-seg), with a
// 3-stage rotating register pipeline (S0/S1/S2, 32-k chunks; load chunk c+64
// issued at the phase computing c -> ~2 phases of slack, covers L2 latency).
// 768 = 8 * 96 so the 3-phase rotation tiles K exactly. VGPR ~190 (frags 96 +
// acc 64 + addr) -> 2 waves/SIMD cap, but grid (396 blocks = 1.55 waves/SIMD)
// is the real limit -- which is fine, since there are no barriers to stall on.
__global__ __launch_bounds__(256, 2) void gemm_k(
        const __bf16* __restrict__ allb,
        __bf16* __restrict__ web, float* __restrict__ wdf) {
    int bx = blockIdx.x;
    const __bf16 *Ab, *Bb; int m0, n0; bool wd;
    if (bx < 384) {                      // WE: 64 m-tiles x 6 n-chunks
        wd = false; Ab = allb; Bb = allb + HNELEM;
        m0 = (bx & 63) * 128; n0 = (bx >> 6) * 128;
    } else {                             // WD: 2 m-tiles x 6 n-chunks
        wd = true; bx -= 384; Ab = allb + HNELEM + 2 * WSZ; Bb = allb + HNELEM + WSZ;
        m0 = (bx & 1) * 128;  n0 = (bx >> 1) * 128;
    }

    const int tid = threadIdx.x, wave = tid >> 6, lane = tid & 63;
    const int wm = (wave >> 1) * 64, wn = (wave & 1) * 64;
    const int lr = lane & 15, q = lane >> 4;

    const __bf16* pA[4]; const __bf16* pB[4];
#pragma unroll
    for (int i = 0; i < 4; ++i) pA[i] = Ab + (size_t)(m0 + wm + i * 16 + lr) * 768 + q * 8;
#pragma unroll
    for (int j = 0; j < 4; ++j) pB[j] = Bb + (size_t)(n0 + wn + j * 16 + lr) * 768 + q * 8;

    f32x4 acc[4][4] = {};
    bf16x8 a0v[4], b0v[4], a1v[4], b1v[4], a2v[4], b2v[4];

    // prologue: S0 @ k=0, S1 @ k=32
#pragma unroll
    for (int i = 0; i < 4; ++i) { a0v[i] = *(const bf16x8*)(pA[i]);      b0v[i] = *(const bf16x8*)(pB[i]); }
#pragma unroll
    for (int i = 0; i < 4; ++i) { a1v[i] = *(const bf16x8*)(pA[i] + 32); b1v[i] = *(const bf16x8*)(pB[i] + 32); }

#define PHASE(SA, SB, LA, LB, KL)                                              \
    {                                                                          \
        if ((KL) < 768) {                                                      \
            _Pragma("unroll")                                                  \
            for (int i = 0; i < 4; ++i) {                                      \
                LA[i] = *(const bf16x8*)(pA[i] + (KL));                        \
                LB[i] = *(const bf16x8*)(pB[i] + (KL));                        \
            }                                                                  \
        }                                                                      \
        _Pragma("unroll")                                                      \
        for (int i = 0; i < 4; ++i)                                            \
            _Pragma("unroll")                                                  \
            for (int j = 0; j < 4; ++j)                                        \
                acc[i][j] = __builtin_amdgcn_mfma_f32_16x16x32_bf16(           \
                    SA[i], SB[j], acc[i][j], 0, 0, 0);                         \
    }

#pragma unroll 1
    for (int k0 = 0; k0 < 768; k0 += 96) {
        PHASE(a0v, b0v, a2v, b2v, k0 + 64)    // compute chunk k0,    load k0+64
        PHASE(a1v, b1v, a0v, b0v, k0 + 96)    // compute chunk k0+32, load k0+96
        PHASE(a2v, b2v, a1v, b1v, k0 + 128)   // compute chunk k0+64, load k0+128
    }
#undef PHASE

#pragma unroll
    for (int i = 0; i < 4; ++i)
#pragma unroll
        for (int j = 0; j < 4; ++j)
#pragma unroll
            for (int r = 0; r < 4; ++r) {
                int row = m0 + wm + i * 16 + q * 4 + r;
                int col = n0 + wn + j * 16 + lr;
                if (!wd) web[(size_t)row * 768 + col] = (__bf16)acc[i][j][r];
                else     wdf[(size_t)row * 768 + col] = acc[i][j][r];
            }
}

// ---------------- scores: LDS-free, register-cached, t-split for occupancy ------
// Block = (b, 16 l rows, 8 t's). 256 thr = 16 ls x 16 hc. Thread owns the 48
// h-elements {hc*8 + j*128 + e}, keeps we (unpacked bf16) and V in registers,
// streams wd[t] (f32, L2-resident) per t. __launch_bounds__(256,4): r2's
// VGPR_Count=60 proved the no-hint build sank we/vv loads into the t-loop;
// 128-VGPR cap keeps them resident. Grid = 16x32x2 = 1024 blocks = 4 blocks/CU
// = 16 waves/CU. Per-(wave,t) uniform skip of fully-masked t (~48%). Reduction
// over hc = 4 shfl_xor. No LDS, no __syncthreads. l0 heavy-first.
__global__ __launch_bounds__(256, 4) void scores_k(
        const __bf16* __restrict__ web, const float* __restrict__ wdf,
        const float* __restrict__ V, const int* __restrict__ Xi,
        float* __restrict__ scores) {
    const int b  = blockIdx.x;
    const int l0 = ((int)gridDim.y - 1 - (int)blockIdx.y) * 16;   // heavy first
    const int t0 = blockIdx.z * 8;
    const int tid = threadIdx.x;
    const int ls = tid >> 4, hc = tid & 15;
    const int l  = l0 + ls;
    const int h0 = hc * 8;

    float we[48], vv[48];
    const __bf16* wr = web + ((size_t)(b * L_ + l)) * H_ + h0;
#pragma unroll
    for (int j = 0; j < 6; ++j) {
        uint4 u = *(const uint4*)(wr + j * 128);
        we[j*8+0] = bf_lo(u.x); we[j*8+1] = bf_hi(u.x);
        we[j*8+2] = bf_lo(u.y); we[j*8+3] = bf_hi(u.y);
        we[j*8+4] = bf_lo(u.z); we[j*8+5] = bf_hi(u.z);
        we[j*8+6] = bf_lo(u.w); we[j*8+7] = bf_hi(u.w);
    }
    const float* vp = V + h0;
#pragma unroll
    for (int j = 0; j < 6; ++j) {
        float4 a = *(const float4*)(vp + j * 128);
        float4 c = *(const float4*)(vp + j * 128 + 4);
        vv[j*8+0] = a.x; vv[j*8+1] = a.y; vv[j*8+2] = a.z; vv[j*8+3] = a.w;
        vv[j*8+4] = c.x; vv[j*8+5] = c.y; vv[j*8+6] = c.z; vv[j*8+7] = c.w;
    }

    const int wmaxl = l0 + ((tid >> 6) << 2) + 3;   // wave covers ls = 4w..4w+3
    const int bT = b * T_;
#pragma unroll 1
    for (int t = t0; t < t0 + 8; ++t) {
        const int X = Xi[bT + t];
        if (wmaxl < X) continue;                    // wave-uniform masked skip
        const float* wdp = wdf + ((size_t)(bT + t)) * H_ + h0;
        float a0 = 0.f, a1 = 0.f, a2 = 0.f, a3 = 0.f;
#pragma unroll
        for (int j = 0; j < 6; ++j) {
            float4 x = *(const float4*)(wdp + j * 128);
            float4 y = *(const float4*)(wdp + j * 128 + 4);
            a0 = fmaf(selu_core(we[j*8+0] + x.x), vv[j*8+0], a0);
            a1 = fmaf(selu_core(we[j*8+1] + x.y), vv[j*8+1], a1);
            a2 = fmaf(selu_core(we[j*8+2] + x.z), vv[j*8+2], a2);
            a3 = fmaf(selu_core(we[j*8+3] + x.w), vv[j*8+3], a3);
            a0 = fmaf(selu_core(we[j*8+4] + y.x), vv[j*8+4], a0);
            a1 = fmaf(selu_core(we[j*8+5] + y.y), vv[j*8+5], a1);
            a2 = fmaf(selu_core(we[j*8+6] + y.z), vv[j*8+6], a2);
            a3 = fmaf(selu_core(we[j*8+7] + y.w), vv[j*8+7], a3);
        }
        float dot = (a0 + a1) + (a2 + a3);
        dot += __shfl_xor(dot, 1);
        dot += __shfl_xor(dot, 2);
        dot += __shfl_xor(dot, 4);
        dot += __shfl_xor(dot, 8);
        if (hc == 0) {
            dot *= SELU_SCALE;
            float sc = dot > 0.0f ? SELU_SCALE * dot
                                  : SELU_SCALE * SELU_ALPHA * (__expf(dot) - 1.0f);
            scores[((size_t)(bT + t)) * L_ + l] = sc;
        }
    }
}

// ---------------- per-(b,t) masked logsumexp + gold + mean (atomic) -------------
__global__ __launch_bounds__(64) void loss_k(
        const float* __restrict__ scores, const int* __restrict__ Xi,
        const int* __restrict__ Yi, float* __restrict__ out) {
    const int bt = blockIdx.x;
    const int lane = threadIdx.x;
    const int X = Xi[bt];
    const int Y = Yi[bt];
    const float* row = scores + (size_t)bt * L_;

    float m = -INFINITY;
    for (int l = X + lane; l < L_; l += 64) m = fmaxf(m, row[l]);
#pragma unroll
    for (int off = 32; off > 0; off >>= 1) m = fmaxf(m, __shfl_xor(m, off));

    float s = 0.0f;
    for (int l = X + lane; l < L_; l += 64) s += __expf(row[l] - m);
#pragma unroll
    for (int off = 32; off > 0; off >>= 1) s += __shfl_xor(s, off);

    if (lane == 0)
        atomicAdd(out, (m + __logf(s) - row[Y]) * (1.0f / (B_ * T_)));
}

// ---------------- launch ----------------
extern "C" void kernel_launch(void* const* d_in, const int* in_sizes, int n_in,
                              void* d_out, int out_size, void* d_ws, size_t ws_size,
                              hipStream_t stream) {
    const float* hn  = (const float*)d_in[0];
    const float* dec = (const float*)d_in[1];
    const float* W1  = (const float*)d_in[2];
    const float* W2  = (const float*)d_in[3];
    const float* V   = (const float*)d_in[4];
    const int*   Xi  = (const int*)d_in[5];
    const int*   Yi  = (const int*)d_in[6];
    float* out = (float*)d_out;

    char* ws = (char*)d_ws;
    size_t off = 0;
    auto alloc = [&](size_t bytes) -> char* {
        char* p = ws + off;
        off += (bytes + 255) & ~(size_t)255;
        return p;
    };
    __bf16* web    = (__bf16*)alloc((size_t)B_ * L_ * H_ * 2);
    float*  wdf    = (float*)alloc((size_t)B_ * T_ * H_ * 4);
    float*  scores = (float*)alloc((size_t)B_ * T_ * L_ * 4);
    __bf16* allb   = (__bf16*)alloc((size_t)ALLELEM * 2);

    prep_k<<<ALLELEM / (256 * 8), 256, 0, stream>>>(hn, dec, W1, W2, Yi, allb, out);
    gemm_k<<<396, 256, 0, stream>>>(allb, web, wdf);
    scores_k<<<dim3(B_, L_ / 16, 2), 256, 0, stream>>>(web, wdf, V, Xi, scores);
    loss_k<<<B_ * T_, 64, 0, stream>>>(scores, Xi, Yi, out);
}

// Round 5
// 172.743 us; speedup vs baseline: 1.0233x; 1.0233x over previous
//
#include <hip/hip_runtime.h>
#include <hip/hip_bf16.h>
#include <math.h>

#define SELU_SCALE 1.0507009873554805f
#define SELU_ALPHA 1.6732632423543772f

static constexpr int B_ = 16, T_ = 16, L_ = 512, H_ = 768;
static constexpr int WSZ = 768 * 768;          // one weight matrix, elements
static constexpr int HNELEM = B_ * L_ * H_;    // 6291456
static constexpr int DJELEM = B_ * T_ * H_;    // 196608
// combined bf16 staging buffer layout: [hn | W1 | W2 | dj-gather]
static constexpr int ALLELEM = HNELEM + 2 * WSZ + DJELEM;   // 7667712 (/2048 = 3744)

typedef __bf16 bf16x8 __attribute__((ext_vector_type(8)));
typedef float  f32x4  __attribute__((ext_vector_type(4)));

__device__ __forceinline__ float bf_lo(unsigned u) { return __uint_as_float(u << 16); }
__device__ __forceinline__ float bf_hi(unsigned u) { return __uint_as_float(u & 0xFFFF0000u); }

__device__ __forceinline__ float selu_core(float x) {
    float e = fmaf(__expf(x), SELU_ALPHA, -SELU_ALPHA);
    return x > 0.0f ? x : e;
}

__device__ __forceinline__ bf16x8 pack8(float4 a, float4 b) {
    bf16x8 o;
    o[0] = (__bf16)a.x; o[1] = (__bf16)a.y; o[2] = (__bf16)a.z; o[3] = (__bf16)a.w;
    o[4] = (__bf16)b.x; o[5] = (__bf16)b.y; o[6] = (__bf16)b.z; o[7] = (__bf16)b.w;
    return o;
}

// ---------------- prep: {hn, W1, W2, dec-gather} -> bf16 (one pass, ~7us) -------
// Converting all gemm operands to bf16 up front lets gemm load MFMA A-fragments
// directly from global (16B/lane, r3/r4-verified pattern). Same RTN rounding as
// the original LDS staging path -> bit-identical results. Zeroes loss accum.
__global__ __launch_bounds__(256) void prep_k(
        const float* __restrict__ hn, const float* __restrict__ dec,
        const float* __restrict__ w1, const float* __restrict__ w2,
        const int* __restrict__ Yi,
        __bf16* __restrict__ allb, float* __restrict__ out) {
    if (blockIdx.x == 0 && threadIdx.x == 0) out[0] = 0.0f;
    int idx = (blockIdx.x * 256 + threadIdx.x) * 8;
    const float* src;
    if (idx < HNELEM) {
        src = hn + idx;
    } else if (idx < HNELEM + WSZ) {
        src = w1 + (idx - HNELEM);
    } else if (idx < HNELEM + 2 * WSZ) {
        src = w2 + (idx - HNELEM - WSZ);
    } else {
        int e = idx - (HNELEM + 2 * WSZ);      // < 196608
        int r = e / 768, c = e - r * 768;      // r = bt, 8 elems stay in-row
        src = dec + ((size_t)((r >> 4) * L_ + Yi[r])) * H_ + c;
    }
    float4 a = *(const float4*)src;
    float4 b = *(const float4*)(src + 4);
    *(bf16x8*)(allb + idx) = pack8(a, b);
}

// ---------------- fused NT GEMM (WE + WD): B-in-LDS, one barrier, 32x32 waves ---
// r4 post-mortem: wave-64x64 direct-global pipeline collapsed in codegen
// (VGPR=88 < the 160 the named stages need; conditional prefetch broke the
// rotation) and the wave count (1.5/SIMD) can't hide latency. This version:
// block = 128m x 32n, 4 waves of 32x32 (2x2 MFMA) -> 6336 waves total; LDS
// holds only the B panel (32x768 bf16, staged ONCE -> single __syncthreads,
// +8 elem row pad: rows start 4 banks apart). Per chunk (32k): 2 A-loads
// (global, vm pipe) + 2 B-ds_reads (lgkm pipe) + 4 MFMA -- the two memory
// latencies overlap. Depth-4 register pipeline, all stage indices compile-time,
// NO conditional loads (main loop prefetches c+4 for c<=19 only -> no
// over-read). XCD map: blockIdx = (m%8) + 8*(n + 24*(m/8)) -> per-XCD A
// working set 1.57MB, fits 4MB L2 -> hn fetched from HBM once.
__global__ __launch_bounds__(256, 3) void gemm_k(
        const __bf16* __restrict__ allb,
        __bf16* __restrict__ web, float* __restrict__ wdf) {
    __shared__ __bf16 Bs[32][776];   // 48.5 KB, 3 blocks/CU

    int bx = blockIdx.x;
    const __bf16 *Ab, *Bb; int m0, n0; bool wd;
    if (bx < 1536) {                       // WE: 64 m-tiles(128) x 24 n-tiles(32)
        wd = false; Ab = allb; Bb = allb + HNELEM;
        int c8 = bx & 7, rest = bx >> 3;
        n0 = (rest % 24) * 32;
        m0 = (c8 + (rest / 24) * 8) * 128;
    } else {                               // WD: 2 m-tiles x 24 n-tiles
        wd = true; int b2 = bx - 1536;
        Ab = allb + HNELEM + 2 * WSZ; Bb = allb + HNELEM + WSZ;
        m0 = (b2 & 1) * 128; n0 = (b2 >> 1) * 32;
    }

    const int tid = threadIdx.x, wave = tid >> 6, lane = tid & 63;
    const int lr = lane & 15, q = lane >> 4;

    // ---- stage B panel (32 rows x 768 k): 256 thr x 12 x 16B ----
    {
        int row = tid >> 3, k0 = (tid & 7) * 8;
        const __bf16* src = Bb + (size_t)(n0 + row) * 768 + k0;
        __bf16* dst = &Bs[row][k0];
#pragma unroll
        for (int s = 0; s < 12; ++s)
            *(bf16x8*)(dst + s * 64) = *(const bf16x8*)(src + s * 64);
    }

    // A fragment pointers: wave owns rows [m0+wave*32, +32)
    const __bf16* pA0 = Ab + (size_t)(m0 + wave * 32 + lr) * 768 + q * 8;
    const __bf16* pA1 = pA0 + (size_t)16 * 768;
    // B fragment LDS pointers
    const __bf16* pB0 = &Bs[lr][q * 8];
    const __bf16* pB1 = &Bs[16 + lr][q * 8];

    f32x4 acc[2][2] = {};
    bf16x8 a0s[4], a1s[4], b0s[4], b1s[4];

    // prologue: A loads for chunks 0..3 (before barrier -- independent of LDS)
#pragma unroll
    for (int s = 0; s < 4; ++s) {
        a0s[s] = *(const bf16x8*)(pA0 + s * 32);
        a1s[s] = *(const bf16x8*)(pA1 + s * 32);
    }
    __syncthreads();
#pragma unroll
    for (int s = 0; s < 4; ++s) {
        b0s[s] = *(const bf16x8*)(pB0 + s * 32);
        b1s[s] = *(const bf16x8*)(pB1 + s * 32);
    }

#define MM(s)                                                                   \
    acc[0][0] = __builtin_amdgcn_mfma_f32_16x16x32_bf16(a0s[s], b0s[s], acc[0][0], 0, 0, 0); \
    acc[0][1] = __builtin_amdgcn_mfma_f32_16x16x32_bf16(a0s[s], b1s[s], acc[0][1], 0, 0, 0); \
    acc[1][0] = __builtin_amdgcn_mfma_f32_16x16x32_bf16(a1s[s], b0s[s], acc[1][0], 0, 0, 0); \
    acc[1][1] = __builtin_amdgcn_mfma_f32_16x16x32_bf16(a1s[s], b1s[s], acc[1][1], 0, 0, 0);

#define STEP(s, c)                                                              \
    {                                                                           \
        MM(s)                                                                   \
        a0s[s] = *(const bf16x8*)(pA0 + ((c) + 4) * 32);                        \
        a1s[s] = *(const bf16x8*)(pA1 + ((c) + 4) * 32);                        \
        b0s[s] = *(const bf16x8*)(pB0 + ((c) + 4) * 32);                        \
        b1s[s] = *(const bf16x8*)(pB1 + ((c) + 4) * 32);                        \
    }

#pragma unroll 1
    for (int c = 0; c < 20; c += 4) {       // compute c..c+3, prefetch c+4..c+7
        STEP(0, c)
        STEP(1, c + 1)
        STEP(2, c + 2)
        STEP(3, c + 3)
    }
    MM(0) MM(1) MM(2) MM(3)                 // chunks 20..23, no prefetch
#undef STEP
#undef MM

#pragma unroll
    for (int i = 0; i < 2; ++i)
#pragma unroll
        for (int j = 0; j < 2; ++j)
#pragma unroll
            for (int r = 0; r < 4; ++r) {
                int row = m0 + wave * 32 + i * 16 + q * 4 + r;
                int col = n0 + j * 16 + lr;
                if (!wd) web[(size_t)row * 768 + col] = (__bf16)acc[i][j][r];
                else     wdf[(size_t)row * 768 + col] = acc[i][j][r];
            }
}

// ---------------- scores: LDS-free, register-cached, t-split for occupancy ------
// Block = (b, 16 l rows, 8 t's). 256 thr = 16 ls x 16 hc. Thread owns the 48
// h-elements {hc*8 + j*128 + e}, keeps we (unpacked bf16) and V in registers,
// streams wd[t] (f32, L2-resident) per t. __launch_bounds__(256,4): r2's
// VGPR_Count=60 proved the no-hint build sank we/vv loads into the t-loop;
// 128-VGPR cap keeps them resident. Grid = 16x32x2 = 1024 blocks = 4 blocks/CU
// = 16 waves/CU. Per-(wave,t) uniform skip of fully-masked t (~48%). Reduction
// over hc = 4 shfl_xor. No LDS, no __syncthreads. l0 heavy-first.
__global__ __launch_bounds__(256, 4) void scores_k(
        const __bf16* __restrict__ web, const float* __restrict__ wdf,
        const float* __restrict__ V, const int* __restrict__ Xi,
        float* __restrict__ scores) {
    const int b  = blockIdx.x;
    const int l0 = ((int)gridDim.y - 1 - (int)blockIdx.y) * 16;   // heavy first
    const int t0 = blockIdx.z * 8;
    const int tid = threadIdx.x;
    const int ls = tid >> 4, hc = tid & 15;
    const int l  = l0 + ls;
    const int h0 = hc * 8;

    float we[48], vv[48];
    const __bf16* wr = web + ((size_t)(b * L_ + l)) * H_ + h0;
#pragma unroll
    for (int j = 0; j < 6; ++j) {
        uint4 u = *(const uint4*)(wr + j * 128);
        we[j*8+0] = bf_lo(u.x); we[j*8+1] = bf_hi(u.x);
        we[j*8+2] = bf_lo(u.y); we[j*8+3] = bf_hi(u.y);
        we[j*8+4] = bf_lo(u.z); we[j*8+5] = bf_hi(u.z);
        we[j*8+6] = bf_lo(u.w); we[j*8+7] = bf_hi(u.w);
    }
    const float* vp = V + h0;
#pragma unroll
    for (int j = 0; j < 6; ++j) {
        float4 a = *(const float4*)(vp + j * 128);
        float4 c = *(const float4*)(vp + j * 128 + 4);
        vv[j*8+0] = a.x; vv[j*8+1] = a.y; vv[j*8+2] = a.z; vv[j*8+3] = a.w;
        vv[j*8+4] = c.x; vv[j*8+5] = c.y; vv[j*8+6] = c.z; vv[j*8+7] = c.w;
    }

    const int wmaxl = l0 + ((tid >> 6) << 2) + 3;   // wave covers ls = 4w..4w+3
    const int bT = b * T_;
#pragma unroll 1
    for (int t = t0; t < t0 + 8; ++t) {
        const int X = Xi[bT + t];
        if (wmaxl < X) continue;                    // wave-uniform masked skip
        const float* wdp = wdf + ((size_t)(bT + t)) * H_ + h0;
        float a0 = 0.f, a1 = 0.f, a2 = 0.f, a3 = 0.f;
#pragma unroll
        for (int j = 0; j < 6; ++j) {
            float4 x = *(const float4*)(wdp + j * 128);
            float4 y = *(const float4*)(wdp + j * 128 + 4);
            a0 = fmaf(selu_core(we[j*8+0] + x.x), vv[j*8+0], a0);
            a1 = fmaf(selu_core(we[j*8+1] + x.y), vv[j*8+1], a1);
            a2 = fmaf(selu_core(we[j*8+2] + x.z), vv[j*8+2], a2);
            a3 = fmaf(selu_core(we[j*8+3] + x.w), vv[j*8+3], a3);
            a0 = fmaf(selu_core(we[j*8+4] + y.x), vv[j*8+4], a0);
            a1 = fmaf(selu_core(we[j*8+5] + y.y), vv[j*8+5], a1);
            a2 = fmaf(selu_core(we[j*8+6] + y.z), vv[j*8+6], a2);
            a3 = fmaf(selu_core(we[j*8+7] + y.w), vv[j*8+7], a3);
        }
        float dot = (a0 + a1) + (a2 + a3);
        dot += __shfl_xor(dot, 1);
        dot += __shfl_xor(dot, 2);
        dot += __shfl_xor(dot, 4);
        dot += __shfl_xor(dot, 8);
        if (hc == 0) {
            dot *= SELU_SCALE;
            float sc = dot > 0.0f ? SELU_SCALE * dot
                                  : SELU_SCALE * SELU_ALPHA * (__expf(dot) - 1.0f);
            scores[((size_t)(bT + t)) * L_ + l] = sc;
        }
    }
}

// ---------------- per-(b,t) masked logsumexp + gold + mean (atomic) -------------
__global__ __launch_bounds__(64) void loss_k(
        const float* __restrict__ scores, const int* __restrict__ Xi,
        const int* __restrict__ Yi, float* __restrict__ out) {
    const int bt = blockIdx.x;
    const int lane = threadIdx.x;
    const int X = Xi[bt];
    const int Y = Yi[bt];
    const float* row = scores + (size_t)bt * L_;

    float m = -INFINITY;
    for (int l = X + lane; l < L_; l += 64) m = fmaxf(m, row[l]);
#pragma unroll
    for (int off = 32; off > 0; off >>= 1) m = fmaxf(m, __shfl_xor(m, off));

    float s = 0.0f;
    for (int l = X + lane; l < L_; l += 64) s += __expf(row[l] - m);
#pragma unroll
    for (int off = 32; off > 0; off >>= 1) s += __shfl_xor(s, off);

    if (lane == 0)
        atomicAdd(out, (m + __logf(s) - row[Y]) * (1.0f / (B_ * T_)));
}

// ---------------- launch ----------------
extern "C" void kernel_launch(void* const* d_in, const int* in_sizes, int n_in,
                              void* d_out, int out_size, void* d_ws, size_t ws_size,
                              hipStream_t stream) {
    const float* hn  = (const float*)d_in[0];
    const float* dec = (const float*)d_in[1];
    const float* W1  = (const float*)d_in[2];
    const float* W2  = (const float*)d_in[3];
    const float* V   = (const float*)d_in[4];
    const int*   Xi  = (const int*)d_in[5];
    const int*   Yi  = (const int*)d_in[6];
    float* out = (float*)d_out;

    char* ws = (char*)d_ws;
    size_t off = 0;
    auto alloc = [&](size_t bytes) -> char* {
        char* p = ws + off;
        off += (bytes + 255) & ~(size_t)255;
        return p;
    };
    __bf16* web    = (__bf16*)alloc((size_t)B_ * L_ * H_ * 2);
    float*  wdf    = (float*)alloc((size_t)B_ * T_ * H_ * 4);
    float*  scores = (float*)alloc((size_t)B_ * T_ * L_ * 4);
    __bf16* allb   = (__bf16*)alloc((size_t)ALLELEM * 2);

    prep_k<<<ALLELEM / (256 * 8), 256, 0, stream>>>(hn, dec, W1, W2, Yi, allb, out);
    gemm_k<<<1536 + 48, 256, 0, stream>>>(allb, web, wdf);
    scores_k<<<dim3(B_, L_ / 16, 2), 256, 0, stream>>>(web, wdf, V, Xi, scores);
    loss_k<<<B_ * T_, 64, 0, stream>>>(scores, Xi, Yi, out);
}

// Round 7
// 153.779 us; speedup vs baseline: 1.1495x; 1.1233x over previous
//
#include <hip/hip_runtime.h>
#include <hip/hip_bf16.h>
#include <math.h>

#define SELU_SCALE 1.0507009873554805f
#define SELU_ALPHA 1.6732632423543772f

static constexpr int B_ = 16, T_ = 16, L_ = 512, H_ = 768;

typedef __bf16 bf16x8 __attribute__((ext_vector_type(8)));
typedef float  f32x4  __attribute__((ext_vector_type(4)));

__device__ __forceinline__ float bf_lo(unsigned u) { return __uint_as_float(u << 16); }
__device__ __forceinline__ float bf_hi(unsigned u) { return __uint_as_float(u & 0xFFFF0000u); }

__device__ __forceinline__ float selu_core(float x) {
    float e = fmaf(__expf(x), SELU_ALPHA, -SELU_ALPHA);
    return x > 0.0f ? x : e;
}

// LDS k-segment slot swizzle: slot = seg ^ ((row>>1)&3). r6 measured 0 conflicts
// for these write/read patterns (16-row x 64B contiguous 1KB per wave-op).
__device__ __forceinline__ int xsw(int r) { return (r >> 1) & 3; }

__device__ __forceinline__ bf16x8 pack8(float4 a, float4 b) {
    bf16x8 o;
    o[0] = (__bf16)a.x; o[1] = (__bf16)a.y; o[2] = (__bf16)a.z; o[3] = (__bf16)a.w;
    o[4] = (__bf16)b.x; o[5] = (__bf16)b.y; o[6] = (__bf16)b.z; o[7] = (__bf16)b.w;
    return o;
}

// ---------------- fused NT GEMM (WE + WD), 128x64 tile for residency ------------
// r5 post-mortem: ALL structures (r0 LDS / r4 direct / r5 B-LDS) land 44-50us at
// MfmaUtil 7-8%; register-prefetch never survives codegen (r0 VGPR=76, r4 VGPR=88,
// r5 VGPR=68 -- all too low for the named stages). The untouched lever is BLOCK
// RESIDENCY: all ran <=2 blocks/CU, so each block's barrier/latency drains are
// exposed. This reverts to r0's proven staging+swizzle (measured 0 LDS conflicts)
// with the tile narrowed to 128m x 64n: grid = 64x12 WE + 24 WD = 792 blocks
// ~= 3.1 blocks/CU, LDS 12KB, acc 4x2. Barrier drains of one block now overlap
// compute of ~2 others. prep_k is deleted: staging converts f32->bf16 in-register
// (bit-identical). XCD: same-m blocks at stride 64 == 0 mod 8 -> same-XCD L2.
// (r6 bench was an infra failure -- "container failed twice" -- resubmitted
// unchanged so the residency hypothesis actually gets measured.)
__global__ __launch_bounds__(256, 3) void gemm_k(
        const float* __restrict__ hn, const float* __restrict__ dec,
        const float* __restrict__ w1, const float* __restrict__ w2,
        const int* __restrict__ Yi,
        __bf16* __restrict__ web, float* __restrict__ wdf,
        float* __restrict__ out) {
    __shared__ __bf16 As[128 * 32];   // 8 KB
    __shared__ __bf16 Bs[64 * 32];    // 4 KB

    const int tid = threadIdx.x;
    if (blockIdx.x == 0 && tid == 0) out[0] = 0.0f;   // for loss_k atomics

    int bx = blockIdx.x;
    const float* Wf; int m0, n0; bool wd;
    if (bx < 768) {                      // WE: 64 m-tiles(128) x 12 n-tiles(64)
        wd = false; Wf = w1;
        m0 = (bx & 63) * 128; n0 = (bx >> 6) * 64;
    } else {                             // WD: 2 m-tiles x 12 n-tiles
        wd = true; bx -= 768; Wf = w2;
        m0 = (bx & 1) * 128;  n0 = (bx >> 1) * 64;
    }

    const int wave = tid >> 6, lane = tid & 63;
    const int wm = (wave >> 1) * 64, wn = (wave & 1) * 32;
    const int lr = lane & 15, q = lane >> 4;

    // A staging: thread -> rows r1 = wave*32+(lane>>2), r1+16; slot s3 = lane&3
    // holds global k-seg g1 = s3 ^ xsw(r1)  (xsw(r1) == xsw(r1+16))
    const int r1 = wave * 32 + (lane >> 2);
    const int s3 = lane & 3;
    const int g1 = s3 ^ xsw(r1);

    const float *aG1, *aG2;
    if (!wd) {
        aG1 = hn + (size_t)(m0 + r1) * 768 + g1 * 8;
        aG2 = aG1 + (size_t)16 * 768;
    } else {
        int bt1 = m0 + r1, bt2 = bt1 + 16;
        aG1 = dec + ((size_t)((bt1 >> 4) * L_ + Yi[bt1])) * 768 + g1 * 8;
        aG2 = dec + ((size_t)((bt2 >> 4) * L_ + Yi[bt2])) * 768 + g1 * 8;
    }
    // B staging: thread -> row rB = tid>>2 (0..63), slot sB = tid&3
    const int rB = tid >> 2, sB = tid & 3, gB = sB ^ xsw(rB);
    const float* bG1 = Wf + (size_t)(n0 + rB) * 768 + gB * 8;

    bf16x8* AsW1 = (bf16x8*)&As[r1 * 32 + s3 * 8];
    bf16x8* AsW2 = (bf16x8*)&As[(r1 + 16) * 32 + s3 * 8];
    bf16x8* BsW1 = (bf16x8*)&Bs[rB * 32 + sB * 8];

    // fragment read offsets (global seg q at slot q^xsw(row))
    int aoff[4], boff[2];
#pragma unroll
    for (int i = 0; i < 4; ++i) {
        int r = wm + i * 16 + lr;
        aoff[i] = r * 32 + (q ^ xsw(r)) * 8;
    }
#pragma unroll
    for (int j = 0; j < 2; ++j) {
        int r = wn + j * 16 + lr;
        boff[j] = r * 32 + (q ^ xsw(r)) * 8;
    }

    f32x4 acc[4][2] = {};

    // prologue: tile k=0 -> set X, tile k=32 -> set Y (statically named)
    float4 xa1a = *(const float4*)(aG1);      float4 xa1b = *(const float4*)(aG1 + 4);
    float4 xa2a = *(const float4*)(aG2);      float4 xa2b = *(const float4*)(aG2 + 4);
    float4 xb1a = *(const float4*)(bG1);      float4 xb1b = *(const float4*)(bG1 + 4);
    float4 ya1a = *(const float4*)(aG1 + 32); float4 ya1b = *(const float4*)(aG1 + 36);
    float4 ya2a = *(const float4*)(aG2 + 32); float4 ya2b = *(const float4*)(aG2 + 36);
    float4 yb1a = *(const float4*)(bG1 + 32); float4 yb1b = *(const float4*)(bG1 + 36);

#pragma unroll 1
    for (int k0 = 0; k0 < 768; k0 += 64) {
        // ======== sub-iter X: tile k0 ========
        {
            *AsW1 = pack8(xa1a, xa1b);
            *AsW2 = pack8(xa2a, xa2b);
            *BsW1 = pack8(xb1a, xb1b);
            asm volatile("s_waitcnt lgkmcnt(0)\n\ts_barrier" ::: "memory");
            if (k0 + 64 < 768) {
                xa1a = *(const float4*)(aG1 + k0 + 64); xa1b = *(const float4*)(aG1 + k0 + 68);
                xa2a = *(const float4*)(aG2 + k0 + 64); xa2b = *(const float4*)(aG2 + k0 + 68);
                xb1a = *(const float4*)(bG1 + k0 + 64); xb1b = *(const float4*)(bG1 + k0 + 68);
            }
            bf16x8 af[4], bfr[2];
#pragma unroll
            for (int i = 0; i < 4; ++i) af[i]  = *(const bf16x8*)&As[aoff[i]];
#pragma unroll
            for (int j = 0; j < 2; ++j) bfr[j] = *(const bf16x8*)&Bs[boff[j]];
#pragma unroll
            for (int i = 0; i < 4; ++i)
#pragma unroll
                for (int j = 0; j < 2; ++j)
                    acc[i][j] = __builtin_amdgcn_mfma_f32_16x16x32_bf16(af[i], bfr[j], acc[i][j], 0, 0, 0);
            asm volatile("s_barrier" ::: "memory");
        }
        // ======== sub-iter Y: tile k0+32 ========
        {
            *AsW1 = pack8(ya1a, ya1b);
            *AsW2 = pack8(ya2a, ya2b);
            *BsW1 = pack8(yb1a, yb1b);
            asm volatile("s_waitcnt lgkmcnt(0)\n\ts_barrier" ::: "memory");
            if (k0 + 96 < 768) {
                ya1a = *(const float4*)(aG1 + k0 + 96); ya1b = *(const float4*)(aG1 + k0 + 100);
                ya2a = *(const float4*)(aG2 + k0 + 96); ya2b = *(const float4*)(aG2 + k0 + 100);
                yb1a = *(const float4*)(bG1 + k0 + 96); yb1b = *(const float4*)(bG1 + k0 + 100);
            }
            bf16x8 af[4], bfr[2];
#pragma unroll
            for (int i = 0; i < 4; ++i) af[i]  = *(const bf16x8*)&As[aoff[i]];
#pragma unroll
            for (int j = 0; j < 2; ++j) bfr[j] = *(const bf16x8*)&Bs[boff[j]];
#pragma unroll
            for (int i = 0; i < 4; ++i)
#pragma unroll
                for (int j = 0; j < 2; ++j)
                    acc[i][j] = __builtin_amdgcn_mfma_f32_16x16x32_bf16(af[i], bfr[j], acc[i][j], 0, 0, 0);
            asm volatile("s_barrier" ::: "memory");
        }
    }

#pragma unroll
    for (int i = 0; i < 4; ++i)
#pragma unroll
        for (int j = 0; j < 2; ++j)
#pragma unroll
            for (int r = 0; r < 4; ++r) {
                int row = m0 + wm + i * 16 + q * 4 + r;
                int col = n0 + wn + j * 16 + lr;
                if (!wd) web[(size_t)row * 768 + col] = (__bf16)acc[i][j][r];
                else     wdf[(size_t)row * 768 + col] = acc[i][j][r];
            }
}

// ---------------- scores: LDS-free, register-cached, t-split for occupancy ------
// Block = (b, 16 l rows, 8 t's). 256 thr = 16 ls x 16 hc. Thread owns the 48
// h-elements {hc*8 + j*128 + e}, keeps we (unpacked bf16) and V in registers,
// streams wd[t] (f32, L2-resident) per t. __launch_bounds__(256,4): r2's
// VGPR_Count=60 proved the no-hint build sank we/vv loads into the t-loop;
// 128-VGPR cap keeps them resident. Grid = 16x32x2 = 1024 blocks = 4 blocks/CU
// = 16 waves/CU. Per-(wave,t) uniform skip of fully-masked t (~48%). Reduction
// over hc = 4 shfl_xor. No LDS, no __syncthreads. l0 heavy-first.
__global__ __launch_bounds__(256, 4) void scores_k(
        const __bf16* __restrict__ web, const float* __restrict__ wdf,
        const float* __restrict__ V, const int* __restrict__ Xi,
        float* __restrict__ scores) {
    const int b  = blockIdx.x;
    const int l0 = ((int)gridDim.y - 1 - (int)blockIdx.y) * 16;   // heavy first
    const int t0 = blockIdx.z * 8;
    const int tid = threadIdx.x;
    const int ls = tid >> 4, hc = tid & 15;
    const int l  = l0 + ls;
    const int h0 = hc * 8;

    float we[48], vv[48];
    const __bf16* wr = web + ((size_t)(b * L_ + l)) * H_ + h0;
#pragma unroll
    for (int j = 0; j < 6; ++j) {
        uint4 u = *(const uint4*)(wr + j * 128);
        we[j*8+0] = bf_lo(u.x); we[j*8+1] = bf_hi(u.x);
        we[j*8+2] = bf_lo(u.y); we[j*8+3] = bf_hi(u.y);
        we[j*8+4] = bf_lo(u.z); we[j*8+5] = bf_hi(u.z);
        we[j*8+6] = bf_lo(u.w); we[j*8+7] = bf_hi(u.w);
    }
    const float* vp = V + h0;
#pragma unroll
    for (int j = 0; j < 6; ++j) {
        float4 a = *(const float4*)(vp + j * 128);
        float4 c = *(const float4*)(vp + j * 128 + 4);
        vv[j*8+0] = a.x; vv[j*8+1] = a.y; vv[j*8+2] = a.z; vv[j*8+3] = a.w;
        vv[j*8+4] = c.x; vv[j*8+5] = c.y; vv[j*8+6] = c.z; vv[j*8+7] = c.w;
    }

    const int wmaxl = l0 + ((tid >> 6) << 2) + 3;   // wave covers ls = 4w..4w+3
    const int bT = b * T_;
#pragma unroll 1
    for (int t = t0; t < t0 + 8; ++t) {
        const int X = Xi[bT + t];
        if (wmaxl < X) continue;                    // wave-uniform masked skip
        const float* wdp = wdf + ((size_t)(bT + t)) * H_ + h0;
        float a0 = 0.f, a1 = 0.f, a2 = 0.f, a3 = 0.f;
#pragma unroll
        for (int j = 0; j < 6; ++j) {
            float4 x = *(const float4*)(wdp + j * 128);
            float4 y = *(const float4*)(wdp + j * 128 + 4);
            a0 = fmaf(selu_core(we[j*8+0] + x.x), vv[j*8+0], a0);
            a1 = fmaf(selu_core(we[j*8+1] + x.y), vv[j*8+1], a1);
            a2 = fmaf(selu_core(we[j*8+2] + x.z), vv[j*8+2], a2);
            a3 = fmaf(selu_core(we[j*8+3] + x.w), vv[j*8+3], a3);
            a0 = fmaf(selu_core(we[j*8+4] + y.x), vv[j*8+4], a0);
            a1 = fmaf(selu_core(we[j*8+5] + y.y), vv[j*8+5], a1);
            a2 = fmaf(selu_core(we[j*8+6] + y.z), vv[j*8+6], a2);
            a3 = fmaf(selu_core(we[j*8+7] + y.w), vv[j*8+7], a3);
        }
        float dot = (a0 + a1) + (a2 + a3);
        dot += __shfl_xor(dot, 1);
        dot += __shfl_xor(dot, 2);
        dot += __shfl_xor(dot, 4);
        dot += __shfl_xor(dot, 8);
        if (hc == 0) {
            dot *= SELU_SCALE;
            float sc = dot > 0.0f ? SELU_SCALE * dot
                                  : SELU_SCALE * SELU_ALPHA * (__expf(dot) - 1.0f);
            scores[((size_t)(bT + t)) * L_ + l] = sc;
        }
    }
}

// ---------------- per-(b,t) masked logsumexp + gold + mean (atomic) -------------
__global__ __launch_bounds__(64) void loss_k(
        const float* __restrict__ scores, const int* __restrict__ Xi,
        const int* __restrict__ Yi, float* __restrict__ out) {
    const int bt = blockIdx.x;
    const int lane = threadIdx.x;
    const int X = Xi[bt];
    const int Y = Yi[bt];
    const float* row = scores + (size_t)bt * L_;

    float m = -INFINITY;
    for (int l = X + lane; l < L_; l += 64) m = fmaxf(m, row[l]);
#pragma unroll
    for (int off = 32; off > 0; off >>= 1) m = fmaxf(m, __shfl_xor(m, off));

    float s = 0.0f;
    for (int l = X + lane; l < L_; l += 64) s += __expf(row[l] - m);
#pragma unroll
    for (int off = 32; off > 0; off >>= 1) s += __shfl_xor(s, off);

    if (lane == 0)
        atomicAdd(out, (m + __logf(s) - row[Y]) * (1.0f / (B_ * T_)));
}

// ---------------- launch ----------------
extern "C" void kernel_launch(void* const* d_in, const int* in_sizes, int n_in,
                              void* d_out, int out_size, void* d_ws, size_t ws_size,
                              hipStream_t stream) {
    const float* hn  = (const float*)d_in[0];
    const float* dec = (const float*)d_in[1];
    const float* W1  = (const float*)d_in[2];
    const float* W2  = (const float*)d_in[3];
    const float* V   = (const float*)d_in[4];
    const int*   Xi  = (const int*)d_in[5];
    const int*   Yi  = (const int*)d_in[6];
    float* out = (float*)d_out;

    char* ws = (char*)d_ws;
    size_t off = 0;
    auto alloc = [&](size_t bytes) -> char* {
        char* p = ws + off;
        off += (bytes + 255) & ~(size_t)255;
        return p;
    };
    __bf16* web    = (__bf16*)alloc((size_t)B_ * L_ * H_ * 2);
    float*  wdf    = (float*)alloc((size_t)B_ * T_ * H_ * 4);
    float*  scores = (float*)alloc((size_t)B_ * T_ * L_ * 4);

    // WE (768 blocks) + WD (24 blocks, self-gathering dj)
    gemm_k<<<768 + 24, 256, 0, stream>>>(hn, dec, W1, W2, Yi, web, wdf, out);
    scores_k<<<dim3(B_, L_ / 16, 2), 256, 0, stream>>>(web, wdf, V, Xi, scores);
    loss_k<<<B_ * T_, 64, 0, stream>>>(scores, Xi, Yi, out);
}

// Round 8
// 148.932 us; speedup vs baseline: 1.1869x; 1.0325x over previous
//
#include <hip/hip_runtime.h>
#include <hip/hip_bf16.h>
#include <math.h>

#define SELU_SCALE 1.0507009873554805f
#define SELU_ALPHA 1.6732632423543772f

static constexpr int B_ = 16, T_ = 16, L_ = 512, H_ = 768;
static constexpr int WSZ = 768 * 768;          // one weight matrix, elements
static constexpr int HNELEM = B_ * L_ * H_;    // 6291456
static constexpr int DJELEM = B_ * T_ * H_;    // 196608
// combined bf16 staging buffer layout: [hn | W1 | W2 | dj-gather]
static constexpr int ALLELEM = HNELEM + 2 * WSZ + DJELEM;   // 7667712 (/2048 = 3744)

typedef __bf16 bf16x8 __attribute__((ext_vector_type(8)));
typedef float  f32x4  __attribute__((ext_vector_type(4)));

__device__ __forceinline__ float bf_lo(unsigned u) { return __uint_as_float(u << 16); }
__device__ __forceinline__ float bf_hi(unsigned u) { return __uint_as_float(u & 0xFFFF0000u); }

__device__ __forceinline__ float selu_core(float x) {
    float e = fmaf(__expf(x), SELU_ALPHA, -SELU_ALPHA);
    return x > 0.0f ? x : e;
}

// LDS k-segment slot swizzle: slot = seg ^ ((row>>1)&3). Measured 0 conflicts
// for these write/read patterns. Note xsw(r+16) == xsw(r), so fragment offsets
// are affine in the 16-row fragment index.
__device__ __forceinline__ int xsw(int r) { return (r >> 1) & 3; }

__device__ __forceinline__ bf16x8 pack8(float4 a, float4 b) {
    bf16x8 o;
    o[0] = (__bf16)a.x; o[1] = (__bf16)a.y; o[2] = (__bf16)a.z; o[3] = (__bf16)a.w;
    o[4] = (__bf16)b.x; o[5] = (__bf16)b.y; o[6] = (__bf16)b.z; o[7] = (__bf16)b.w;
    return o;
}

// ---------------- prep: {hn, W1, W2, dec-gather} -> bf16 (one pass, ~7us) -------
// r3/r4-proven bit-identical (same RTN rounding as the old in-register staging).
// Enables gemm_k's global_load_lds DMA staging (no dtype conversion possible in
// the DMA path). Also zeroes the loss accumulator.
__global__ __launch_bounds__(256) void prep_k(
        const float* __restrict__ hn, const float* __restrict__ dec,
        const float* __restrict__ w1, const float* __restrict__ w2,
        const int* __restrict__ Yi,
        __bf16* __restrict__ allb, float* __restrict__ out) {
    if (blockIdx.x == 0 && threadIdx.x == 0) out[0] = 0.0f;
    int idx = (blockIdx.x * 256 + threadIdx.x) * 8;
    const float* src;
    if (idx < HNELEM) {
        src = hn + idx;
    } else if (idx < HNELEM + WSZ) {
        src = w1 + (idx - HNELEM);
    } else if (idx < HNELEM + 2 * WSZ) {
        src = w2 + (idx - HNELEM - WSZ);
    } else {
        int e = idx - (HNELEM + 2 * WSZ);      // < 196608
        int r = e / 768, c = e - r * 768;      // r = bt, 8 elems stay in-row
        src = dec + ((size_t)((r >> 4) * L_ + Yi[r])) * H_ + c;
    }
    float4 a = *(const float4*)src;
    float4 b = *(const float4*)(src + 4);
    *(bf16x8*)(allb + idx) = pack8(a, b);
}

// ---------------- fused NT GEMM: global_load_lds + 2-phase double buffer --------
// r7 falsified the residency hypothesis (3.1 blk/CU, still 44.9us, MfmaUtil 7.7%).
// The stall is the per-sub-iter chain: f32 load->VGPR->vmcnt(0)->pack->ds_write->
// lgkm(0)->barrier->ds_read->MFMA->barrier, 48 barriers. This is the guide's T3
// 2-phase recipe with global_load_lds(16B): staging is fire-and-forget DMA into
// buf^1 while MFMA consumes buf; ONE vmcnt(0)+barrier per k-step (24 total).
// Source addresses are PRE-SWIZZLED with xsw (LDS stays linear, per m104/m173);
// fragment ds_reads use the measured-0-conflict offsets. 128x128 tile, BK=32,
// 32KB LDS dbuf, 4 waves of 64x64 (4x4 16x16x32 MFMA). Grid 396 (1.55 blk/CU):
// fine -- latency hides under same-block compute now, not co-residency.
__global__ __launch_bounds__(256, 2) void gemm_k(
        const __bf16* __restrict__ allb,
        __bf16* __restrict__ web, float* __restrict__ wdf) {
    __shared__ __bf16 sm[2][2][4096];   // [buf][A/B][128*32] = 32 KB

    int bx = blockIdx.x;
    const __bf16 *Ab, *Bb; int m0, n0; bool wd;
    if (bx < 384) {                      // WE: 64 m-tiles x 6 n-chunks
        wd = false; Ab = allb; Bb = allb + HNELEM;
        m0 = (bx & 63) * 128; n0 = (bx >> 6) * 128;
    } else {                             // WD: 2 m-tiles x 6 n-chunks
        wd = true; bx -= 384;
        Ab = allb + HNELEM + 2 * WSZ; Bb = allb + HNELEM + WSZ;
        m0 = (bx & 1) * 128;  n0 = (bx >> 1) * 128;
    }

    const int tid = threadIdx.x, wave = tid >> 6, lane = tid & 63;
    const int wm = (wave >> 1) * 64, wn = (wave & 1) * 64;
    const int lr = lane & 15, q = lane >> 4;
    const int l4 = lane >> 2, sl = lane & 3;

    // staging rows: instr0 -> rows wave*16 + l4 (0..63), instr1 -> +64.
    // lane's 16B lands at ldsBase + lane*16 (linear); pre-swizzled global seg.
    const int ar0 = wave * 16 + l4, ar1 = ar0 + 64;
    const __bf16* gA0 = Ab + (size_t)(m0 + ar0) * 768 + (sl ^ xsw(ar0)) * 8;
    const __bf16* gA1 = Ab + (size_t)(m0 + ar1) * 768 + (sl ^ xsw(ar1)) * 8;
    const __bf16* gB0 = Bb + (size_t)(n0 + ar0) * 768 + (sl ^ xsw(ar0)) * 8;
    const __bf16* gB1 = Bb + (size_t)(n0 + ar1) * 768 + (sl ^ xsw(ar1)) * 8;
    const int ld0 = wave * 512;          // element offset of this wave's 1KB slice
    const int ld1 = 2048 + wave * 512;

    // fragment base offsets (xsw(r+16)==xsw(r) -> affine in fragment index)
    const int aoff0 = (wm + lr) * 32 + (q ^ xsw(wm + lr)) * 8;
    const int boff0 = (wn + lr) * 32 + (q ^ xsw(wn + lr)) * 8;

    f32x4 acc[4][4] = {};

#define STAGE(b, kk)                                                                        \
    {                                                                                       \
        __builtin_amdgcn_global_load_lds((const __attribute__((address_space(1))) void*)(gA0 + (kk)), \
            (__attribute__((address_space(3))) void*)&sm[b][0][ld0], 16, 0, 0);             \
        __builtin_amdgcn_global_load_lds((const __attribute__((address_space(1))) void*)(gA1 + (kk)), \
            (__attribute__((address_space(3))) void*)&sm[b][0][ld1], 16, 0, 0);             \
        __builtin_amdgcn_global_load_lds((const __attribute__((address_space(1))) void*)(gB0 + (kk)), \
            (__attribute__((address_space(3))) void*)&sm[b][1][ld0], 16, 0, 0);             \
        __builtin_amdgcn_global_load_lds((const __attribute__((address_space(1))) void*)(gB1 + (kk)), \
            (__attribute__((address_space(3))) void*)&sm[b][1][ld1], 16, 0, 0);             \
    }

#define COMPUTE(b)                                                                          \
    {                                                                                       \
        bf16x8 af[4], bfr[4];                                                               \
        _Pragma("unroll")                                                                   \
        for (int i = 0; i < 4; ++i) af[i]  = *(const bf16x8*)&sm[b][0][aoff0 + i * 512];    \
        _Pragma("unroll")                                                                   \
        for (int j = 0; j < 4; ++j) bfr[j] = *(const bf16x8*)&sm[b][1][boff0 + j * 512];    \
        _Pragma("unroll")                                                                   \
        for (int i = 0; i < 4; ++i)                                                         \
            _Pragma("unroll")                                                               \
            for (int j = 0; j < 4; ++j)                                                     \
                acc[i][j] = __builtin_amdgcn_mfma_f32_16x16x32_bf16(af[i], bfr[j], acc[i][j], 0, 0, 0); \
    }

    // prologue: stage tile 0, drain, barrier
    STAGE(0, 0)
    asm volatile("s_waitcnt vmcnt(0)" ::: "memory");
    __builtin_amdgcn_s_barrier();

    int cur = 0;
#pragma unroll 1
    for (int t = 0; t < 23; ++t) {
        STAGE(cur ^ 1, (t + 1) * 32)     // issue next tile (fire-and-forget DMA)
        COMPUTE(cur)                     // ds_read + MFMA current tile
        asm volatile("s_waitcnt vmcnt(0)" ::: "memory");
        __builtin_amdgcn_s_barrier();    // next tile ready; everyone done reading cur
        cur ^= 1;
    }
    COMPUTE(cur)                         // last tile, no prefetch
#undef STAGE
#undef COMPUTE

#pragma unroll
    for (int i = 0; i < 4; ++i)
#pragma unroll
        for (int j = 0; j < 4; ++j)
#pragma unroll
            for (int r = 0; r < 4; ++r) {
                int row = m0 + wm + i * 16 + q * 4 + r;
                int col = n0 + wn + j * 16 + lr;
                if (!wd) web[(size_t)row * 768 + col] = (__bf16)acc[i][j][r];
                else     wdf[(size_t)row * 768 + col] = acc[i][j][r];
            }
}

// ---------------- scores: LDS-free, register-cached, t-split for occupancy ------
// Block = (b, 16 l rows, 8 t's). 256 thr = 16 ls x 16 hc. Thread owns the 48
// h-elements {hc*8 + j*128 + e}, keeps we (unpacked bf16) and V in registers,
// streams wd[t] (f32, L2-resident) per t. __launch_bounds__(256,4): r2's
// VGPR_Count=60 proved the no-hint build sank we/vv loads into the t-loop;
// 128-VGPR cap keeps them resident. Grid = 16x32x2 = 1024 blocks = 4 blocks/CU
// = 16 waves/CU. Per-(wave,t) uniform skip of fully-masked t (~48%). Reduction
// over hc = 4 shfl_xor. No LDS, no __syncthreads. l0 heavy-first.
__global__ __launch_bounds__(256, 4) void scores_k(
        const __bf16* __restrict__ web, const float* __restrict__ wdf,
        const float* __restrict__ V, const int* __restrict__ Xi,
        float* __restrict__ scores) {
    const int b  = blockIdx.x;
    const int l0 = ((int)gridDim.y - 1 - (int)blockIdx.y) * 16;   // heavy first
    const int t0 = blockIdx.z * 8;
    const int tid = threadIdx.x;
    const int ls = tid >> 4, hc = tid & 15;
    const int l  = l0 + ls;
    const int h0 = hc * 8;

    float we[48], vv[48];
    const __bf16* wr = web + ((size_t)(b * L_ + l)) * H_ + h0;
#pragma unroll
    for (int j = 0; j < 6; ++j) {
        uint4 u = *(const uint4*)(wr + j * 128);
        we[j*8+0] = bf_lo(u.x); we[j*8+1] = bf_hi(u.x);
        we[j*8+2] = bf_lo(u.y); we[j*8+3] = bf_hi(u.y);
        we[j*8+4] = bf_lo(u.z); we[j*8+5] = bf_hi(u.z);
        we[j*8+6] = bf_lo(u.w); we[j*8+7] = bf_hi(u.w);
    }
    const float* vp = V + h0;
#pragma unroll
    for (int j = 0; j < 6; ++j) {
        float4 a = *(const float4*)(vp + j * 128);
        float4 c = *(const float4*)(vp + j * 128 + 4);
        vv[j*8+0] = a.x; vv[j*8+1] = a.y; vv[j*8+2] = a.z; vv[j*8+3] = a.w;
        vv[j*8+4] = c.x; vv[j*8+5] = c.y; vv[j*8+6] = c.z; vv[j*8+7] = c.w;
    }

    const int wmaxl = l0 + ((tid >> 6) << 2) + 3;   // wave covers ls = 4w..4w+3
    const int bT = b * T_;
#pragma unroll 1
    for (int t = t0; t < t0 + 8; ++t) {
        const int X = Xi[bT + t];
        if (wmaxl < X) continue;                    // wave-uniform masked skip
        const float* wdp = wdf + ((size_t)(bT + t)) * H_ + h0;
        float a0 = 0.f, a1 = 0.f, a2 = 0.f, a3 = 0.f;
#pragma unroll
        for (int j = 0; j < 6; ++j) {
            float4 x = *(const float4*)(wdp + j * 128);
            float4 y = *(const float4*)(wdp + j * 128 + 4);
            a0 = fmaf(selu_core(we[j*8+0] + x.x), vv[j*8+0], a0);
            a1 = fmaf(selu_core(we[j*8+1] + x.y), vv[j*8+1], a1);
            a2 = fmaf(selu_core(we[j*8+2] + x.z), vv[j*8+2], a2);
            a3 = fmaf(selu_core(we[j*8+3] + x.w), vv[j*8+3], a3);
            a0 = fmaf(selu_core(we[j*8+4] + y.x), vv[j*8+4], a0);
            a1 = fmaf(selu_core(we[j*8+5] + y.y), vv[j*8+5], a1);
            a2 = fmaf(selu_core(we[j*8+6] + y.z), vv[j*8+6], a2);
            a3 = fmaf(selu_core(we[j*8+7] + y.w), vv[j*8+7], a3);
        }
        float dot = (a0 + a1) + (a2 + a3);
        dot += __shfl_xor(dot, 1);
        dot += __shfl_xor(dot, 2);
        dot += __shfl_xor(dot, 4);
        dot += __shfl_xor(dot, 8);
        if (hc == 0) {
            dot *= SELU_SCALE;
            float sc = dot > 0.0f ? SELU_SCALE * dot
                                  : SELU_SCALE * SELU_ALPHA * (__expf(dot) - 1.0f);
            scores[((size_t)(bT + t)) * L_ + l] = sc;
        }
    }
}

// ---------------- per-(b,t) masked logsumexp + gold + mean (atomic) -------------
__global__ __launch_bounds__(64) void loss_k(
        const float* __restrict__ scores, const int* __restrict__ Xi,
        const int* __restrict__ Yi, float* __restrict__ out) {
    const int bt = blockIdx.x;
    const int lane = threadIdx.x;
    const int X = Xi[bt];
    const int Y = Yi[bt];
    const float* row = scores + (size_t)bt * L_;

    float m = -INFINITY;
    for (int l = X + lane; l < L_; l += 64) m = fmaxf(m, row[l]);
#pragma unroll
    for (int off = 32; off > 0; off >>= 1) m = fmaxf(m, __shfl_xor(m, off));

    float s = 0.0f;
    for (int l = X + lane; l < L_; l += 64) s += __expf(row[l] - m);
#pragma unroll
    for (int off = 32; off > 0; off >>= 1) s += __shfl_xor(s, off);

    if (lane == 0)
        atomicAdd(out, (m + __logf(s) - row[Y]) * (1.0f / (B_ * T_)));
}

// ---------------- launch ----------------
extern "C" void kernel_launch(void* const* d_in, const int* in_sizes, int n_in,
                              void* d_out, int out_size, void* d_ws, size_t ws_size,
                              hipStream_t stream) {
    const float* hn  = (const float*)d_in[0];
    const float* dec = (const float*)d_in[1];
    const float* W1  = (const float*)d_in[2];
    const float* W2  = (const float*)d_in[3];
    const float* V   = (const float*)d_in[4];
    const int*   Xi  = (const int*)d_in[5];
    const int*   Yi  = (const int*)d_in[6];
    float* out = (float*)d_out;

    char* ws = (char*)d_ws;
    size_t off = 0;
    auto alloc = [&](size_t bytes) -> char* {
        char* p = ws + off;
        off += (bytes + 255) & ~(size_t)255;
        return p;
    };
    __bf16* web    = (__bf16*)alloc((size_t)B_ * L_ * H_ * 2);
    float*  wdf    = (float*)alloc((size_t)B_ * T_ * H_ * 4);
    float*  scores = (float*)alloc((size_t)B_ * T_ * L_ * 4);
    __bf16* allb   = (__bf16*)alloc((size_t)ALLELEM * 2);

    prep_k<<<ALLELEM / (256 * 8), 256, 0, stream>>>(hn, dec, W1, W2, Yi, allb, out);
    gemm_k<<<396, 256, 0, stream>>>(allb, web, wdf);
    scores_k<<<dim3(B_, L_ / 16, 2), 256, 0, stream>>>(web, wdf, V, Xi, scores);
    loss_k<<<B_ * T_, 64, 0, stream>>>(scores, Xi, Yi, out);
}

// Round 10
// 145.149 us; speedup vs baseline: 1.2179x; 1.0261x over previous
//
#include <hip/hip_runtime.h>
#include <hip/hip_bf16.h>
#include <math.h>

#define SELU_SCALE 1.0507009873554805f
#define SELU_ALPHA 1.6732632423543772f

static constexpr int B_ = 16, T_ = 16, L_ = 512, H_ = 768;
static constexpr int WSZ = 768 * 768;          // one weight matrix, elements
static constexpr int HNELEM = B_ * L_ * H_;    // 6291456
static constexpr int DJELEM = B_ * T_ * H_;    // 196608
// combined bf16 staging buffer layout: [hn | W1 | W2 | dj-gather]
static constexpr int ALLELEM = HNELEM + 2 * WSZ + DJELEM;   // 7667712 (/2048 = 3744)

typedef __bf16 bf16x8 __attribute__((ext_vector_type(8)));
typedef float  f32x4  __attribute__((ext_vector_type(4)));

__device__ __forceinline__ float bf_lo(unsigned u) { return __uint_as_float(u << 16); }
__device__ __forceinline__ float bf_hi(unsigned u) { return __uint_as_float(u & 0xFFFF0000u); }

__device__ __forceinline__ float selu_core(float x) {
    float e = fmaf(__expf(x), SELU_ALPHA, -SELU_ALPHA);
    return x > 0.0f ? x : e;
}

// LDS k-segment slot swizzle: slot = seg ^ ((row>>1)&3). Measured 0 conflicts
// for these write/read patterns. Note xsw(r+16) == xsw(r), so fragment offsets
// are affine in the 16-row fragment index.
__device__ __forceinline__ int xsw(int r) { return (r >> 1) & 3; }

__device__ __forceinline__ bf16x8 pack8(float4 a, float4 b) {
    bf16x8 o;
    o[0] = (__bf16)a.x; o[1] = (__bf16)a.y; o[2] = (__bf16)a.z; o[3] = (__bf16)a.w;
    o[4] = (__bf16)b.x; o[5] = (__bf16)b.y; o[6] = (__bf16)b.z; o[7] = (__bf16)b.w;
    return o;
}

// ---------------- prep: {hn, W1, W2, dec-gather} -> bf16 (one pass, ~7us) -------
// r3/r4-proven bit-identical (same RTN rounding as the old in-register staging).
// Enables gemm_k's global_load_lds DMA staging. Also zeroes the loss accumulator.
__global__ __launch_bounds__(256) void prep_k(
        const float* __restrict__ hn, const float* __restrict__ dec,
        const float* __restrict__ w1, const float* __restrict__ w2,
        const int* __restrict__ Yi,
        __bf16* __restrict__ allb, float* __restrict__ out) {
    if (blockIdx.x == 0 && threadIdx.x == 0) out[0] = 0.0f;
    int idx = (blockIdx.x * 256 + threadIdx.x) * 8;
    const float* src;
    if (idx < HNELEM) {
        src = hn + idx;
    } else if (idx < HNELEM + WSZ) {
        src = w1 + (idx - HNELEM);
    } else if (idx < HNELEM + 2 * WSZ) {
        src = w2 + (idx - HNELEM - WSZ);
    } else {
        int e = idx - (HNELEM + 2 * WSZ);      // < 196608
        int r = e / 768, c = e - r * 768;      // r = bt, 8 elems stay in-row
        src = dec + ((size_t)((r >> 4) * L_ + Yi[r])) * H_ + c;
    }
    float4 a = *(const float4*)src;
    float4 b = *(const float4*)(src + 4);
    *(bf16x8*)(allb + idx) = pack8(a, b);
}

// ---------------- fused NT GEMM: global_load_lds + counted-vmcnt 3-buffer -------
// r8 (2-phase gload_lds, vmcnt(0)/step) dropped gemm below the fill threshold.
// T4 applied: 3 LDS buffers, prefetch distance 2, s_waitcnt vmcnt(4) in the
// steady state -- never 0 -- so the newest stage's 4 DMA loads stay in flight
// across the barrier (in-order vm retirement => the oldest stage has landed).
// r9 AUDIT FIX: at the FINAL tile (23) only 4 ops are outstanding, so vmcnt(4)
// passed without ensuring tile 23 landed -- a read-before-DMA race. The last
// step is now peeled with vmcnt(0)+barrier. Steady-state race audit unchanged:
// STAGE(t+2) issues AFTER barrier(t); buf[(t+2)%3] was last read at iter t-1,
// sealed by that same barrier (ds_reads complete before MFMA use, hence before
// the barrier). sched_barrier(0) pins COMPUTE's ds_reads below the sync.
// 128x128 tile, BK=32, 48KB LDS, 4 waves of 64x64, pre-swizzled DMA source
// (xsw; LDS linear per m104/m173), measured-0-conflict fragment reads.
__global__ __launch_bounds__(256, 2) void gemm_k(
        const __bf16* __restrict__ allb,
        __bf16* __restrict__ web, float* __restrict__ wdf) {
    __shared__ __bf16 sm[3][2][4096];   // [buf][A/B][128*32] = 48 KB

    int bx = blockIdx.x;
    const __bf16 *Ab, *Bb; int m0, n0; bool wd;
    if (bx < 384) {                      // WE: 64 m-tiles x 6 n-chunks
        wd = false; Ab = allb; Bb = allb + HNELEM;
        m0 = (bx & 63) * 128; n0 = (bx >> 6) * 128;
    } else {                             // WD: 2 m-tiles x 6 n-chunks
        wd = true; bx -= 384;
        Ab = allb + HNELEM + 2 * WSZ; Bb = allb + HNELEM + WSZ;
        m0 = (bx & 1) * 128;  n0 = (bx >> 1) * 128;
    }

    const int tid = threadIdx.x, wave = tid >> 6, lane = tid & 63;
    const int wm = (wave >> 1) * 64, wn = (wave & 1) * 64;
    const int lr = lane & 15, q = lane >> 4;
    const int l4 = lane >> 2, sl = lane & 3;

    // staging rows: instr0 -> rows wave*16 + l4 (0..63), instr1 -> +64.
    // lane's 16B lands at ldsBase + lane*16 (linear); pre-swizzled global seg.
    const int ar0 = wave * 16 + l4, ar1 = ar0 + 64;
    const __bf16* gA0 = Ab + (size_t)(m0 + ar0) * 768 + (sl ^ xsw(ar0)) * 8;
    const __bf16* gA1 = Ab + (size_t)(m0 + ar1) * 768 + (sl ^ xsw(ar1)) * 8;
    const __bf16* gB0 = Bb + (size_t)(n0 + ar0) * 768 + (sl ^ xsw(ar0)) * 8;
    const __bf16* gB1 = Bb + (size_t)(n0 + ar1) * 768 + (sl ^ xsw(ar1)) * 8;
    const int ld0 = wave * 512;          // element offset of this wave's 1KB slice
    const int ld1 = 2048 + wave * 512;

    // fragment base offsets (xsw(r+16)==xsw(r) -> affine in fragment index)
    const int aoff0 = (wm + lr) * 32 + (q ^ xsw(wm + lr)) * 8;
    const int boff0 = (wn + lr) * 32 + (q ^ xsw(wn + lr)) * 8;

    f32x4 acc[4][4] = {};

#define STAGE(b, kk)                                                                        \
    {                                                                                       \
        __builtin_amdgcn_global_load_lds((const __attribute__((address_space(1))) void*)(gA0 + (kk)), \
            (__attribute__((address_space(3))) void*)&sm[b][0][ld0], 16, 0, 0);             \
        __builtin_amdgcn_global_load_lds((const __attribute__((address_space(1))) void*)(gA1 + (kk)), \
            (__attribute__((address_space(3))) void*)&sm[b][0][ld1], 16, 0, 0);             \
        __builtin_amdgcn_global_load_lds((const __attribute__((address_space(1))) void*)(gB0 + (kk)), \
            (__attribute__((address_space(3))) void*)&sm[b][1][ld0], 16, 0, 0);             \
        __builtin_amdgcn_global_load_lds((const __attribute__((address_space(1))) void*)(gB1 + (kk)), \
            (__attribute__((address_space(3))) void*)&sm[b][1][ld1], 16, 0, 0);             \
    }

#define COMPUTE(b)                                                                          \
    {                                                                                       \
        bf16x8 af[4], bfr[4];                                                               \
        _Pragma("unroll")                                                                   \
        for (int i = 0; i < 4; ++i) af[i]  = *(const bf16x8*)&sm[b][0][aoff0 + i * 512];    \
        _Pragma("unroll")                                                                   \
        for (int j = 0; j < 4; ++j) bfr[j] = *(const bf16x8*)&sm[b][1][boff0 + j * 512];    \
        _Pragma("unroll")                                                                   \
        for (int i = 0; i < 4; ++i)                                                         \
            _Pragma("unroll")                                                               \
            for (int j = 0; j < 4; ++j)                                                     \
                acc[i][j] = __builtin_amdgcn_mfma_f32_16x16x32_bf16(af[i], bfr[j], acc[i][j], 0, 0, 0); \
    }

// one steady-state k-step: wait until the oldest in-flight stage landed
// (<=4 outstanding, in-order retirement), barrier, prefetch tile tt+2, compute
// tile tt. Valid for tt <= 22 (two stages in flight at the wait).
#define ITER(tt, bc, bs)                                                                    \
    {                                                                                       \
        asm volatile("s_waitcnt vmcnt(4)" ::: "memory");                                    \
        __builtin_amdgcn_s_barrier();                                                       \
        __builtin_amdgcn_sched_barrier(0);                                                  \
        if ((tt) + 2 < 24) STAGE(bs, ((tt) + 2) * 32)                                       \
        COMPUTE(bc)                                                                         \
    }

    // prologue: stage tiles 0 and 1 (no drain -- ITER's vmcnt(4) covers it)
    STAGE(0, 0)
    STAGE(1, 32)

#pragma unroll 1
    for (int g = 0; g < 7; ++g) {       // tiles 0..20
        const int t0g = g * 3;
        ITER(t0g + 0, 0, 2)
        ITER(t0g + 1, 1, 0)
        ITER(t0g + 2, 2, 1)
    }
    ITER(21, 0, 2)                      // stages tile 23 into buf 2
    ITER(22, 1, 0)                      // stages nothing
    // FINAL tile 23: only 4 ops outstanding here -- vmcnt(4) would NOT wait
    // (the r9 race). Drain fully, then one barrier so all waves' DMA is visible.
    asm volatile("s_waitcnt vmcnt(0)" ::: "memory");
    __builtin_amdgcn_s_barrier();
    __builtin_amdgcn_sched_barrier(0);
    COMPUTE(2)
#undef ITER
#undef STAGE
#undef COMPUTE

#pragma unroll
    for (int i = 0; i < 4; ++i)
#pragma unroll
        for (int j = 0; j < 4; ++j)
#pragma unroll
            for (int r = 0; r < 4; ++r) {
                int row = m0 + wm + i * 16 + q * 4 + r;
                int col = n0 + wn + j * 16 + lr;
                if (!wd) web[(size_t)row * 768 + col] = (__bf16)acc[i][j][r];
                else     wdf[(size_t)row * 768 + col] = acc[i][j][r];
            }
}

// ---------------- scores: LDS-free, register-cached, prefix-t + unroll 2 --------
// Block = (b, 16 l rows, 8 t's). 256 thr = 16 ls x 16 hc. Thread owns the 48
// h-elements {hc*8 + j*128 + e}, keeps we (unpacked bf16) and V in registers,
// streams wd[t] (f32, L2-resident) per t. Xindex is strictly monotone in t
// (32t), so per-wave valid t's form a PREFIX: compute tend once, loop
// branch-free, and early-exit fully-masked waves BEFORE the 24 we/vv loads.
// #pragma unroll 2 interleaves two t's 12-load chains (loop is L2-latency-bound
// at 4 waves/SIMD). lb(256,4) keeps we/vv hoisted (r2: no-hint sank them).
__global__ __launch_bounds__(256, 4) void scores_k(
        const __bf16* __restrict__ web, const float* __restrict__ wdf,
        const float* __restrict__ V, const int* __restrict__ Xi,
        float* __restrict__ scores) {
    const int b  = blockIdx.x;
    const int l0 = ((int)gridDim.y - 1 - (int)blockIdx.y) * 16;   // heavy first
    const int t0 = blockIdx.z * 8;
    const int tid = threadIdx.x;
    const int ls = tid >> 4, hc = tid & 15;
    const int l  = l0 + ls;
    const int h0 = hc * 8;
    const int bT = b * T_;

    const int wmaxl = l0 + ((tid >> 6) << 2) + 3;   // wave covers ls = 4w..4w+3
    if (wmaxl < Xi[bT + t0]) return;                // whole window masked (prefix)
    int tend = t0;
#pragma unroll
    for (int tt = t0; tt < t0 + 8; ++tt)
        if (wmaxl >= Xi[bT + tt]) tend = tt + 1;    // valid t's are a prefix

    float we[48], vv[48];
    const __bf16* wr = web + ((size_t)(b * L_ + l)) * H_ + h0;
#pragma unroll
    for (int j = 0; j < 6; ++j) {
        uint4 u = *(const uint4*)(wr + j * 128);
        we[j*8+0] = bf_lo(u.x); we[j*8+1] = bf_hi(u.x);
        we[j*8+2] = bf_lo(u.y); we[j*8+3] = bf_hi(u.y);
        we[j*8+4] = bf_lo(u.z); we[j*8+5] = bf_hi(u.z);
        we[j*8+6] = bf_lo(u.w); we[j*8+7] = bf_hi(u.w);
    }
    const float* vp = V + h0;
#pragma unroll
    for (int j = 0; j < 6; ++j) {
        float4 a = *(const float4*)(vp + j * 128);
        float4 c = *(const float4*)(vp + j * 128 + 4);
        vv[j*8+0] = a.x; vv[j*8+1] = a.y; vv[j*8+2] = a.z; vv[j*8+3] = a.w;
        vv[j*8+4] = c.x; vv[j*8+5] = c.y; vv[j*8+6] = c.z; vv[j*8+7] = c.w;
    }

#pragma unroll 2
    for (int t = t0; t < tend; ++t) {
        const float* wdp = wdf + ((size_t)(bT + t)) * H_ + h0;
        float a0 = 0.f, a1 = 0.f, a2 = 0.f, a3 = 0.f;
#pragma unroll
        for (int j = 0; j < 6; ++j) {
            float4 x = *(const float4*)(wdp + j * 128);
            float4 y = *(const float4*)(wdp + j * 128 + 4);
            a0 = fmaf(selu_core(we[j*8+0] + x.x), vv[j*8+0], a0);
            a1 = fmaf(selu_core(we[j*8+1] + x.y), vv[j*8+1], a1);
            a2 = fmaf(selu_core(we[j*8+2] + x.z), vv[j*8+2], a2);
            a3 = fmaf(selu_core(we[j*8+3] + x.w), vv[j*8+3], a3);
            a0 = fmaf(selu_core(we[j*8+4] + y.x), vv[j*8+4], a0);
            a1 = fmaf(selu_core(we[j*8+5] + y.y), vv[j*8+5], a1);
            a2 = fmaf(selu_core(we[j*8+6] + y.z), vv[j*8+6], a2);
            a3 = fmaf(selu_core(we[j*8+7] + y.w), vv[j*8+7], a3);
        }
        float dot = (a0 + a1) + (a2 + a3);
        dot += __shfl_xor(dot, 1);
        dot += __shfl_xor(dot, 2);
        dot += __shfl_xor(dot, 4);
        dot += __shfl_xor(dot, 8);
        if (hc == 0) {
            dot *= SELU_SCALE;
            float sc = dot > 0.0f ? SELU_SCALE * dot
                                  : SELU_SCALE * SELU_ALPHA * (__expf(dot) - 1.0f);
            scores[((size_t)(bT + t)) * L_ + l] = sc;
        }
    }
}

// ---------------- per-(b,t) masked logsumexp + gold + mean (atomic) -------------
__global__ __launch_bounds__(64) void loss_k(
        const float* __restrict__ scores, const int* __restrict__ Xi,
        const int* __restrict__ Yi, float* __restrict__ out) {
    const int bt = blockIdx.x;
    const int lane = threadIdx.x;
    const int X = Xi[bt];
    const int Y = Yi[bt];
    const float* row = scores + (size_t)bt * L_;

    float m = -INFINITY;
    for (int l = X + lane; l < L_; l += 64) m = fmaxf(m, row[l]);
#pragma unroll
    for (int off = 32; off > 0; off >>= 1) m = fmaxf(m, __shfl_xor(m, off));

    float s = 0.0f;
    for (int l = X + lane; l < L_; l += 64) s += __expf(row[l] - m);
#pragma unroll
    for (int off = 32; off > 0; off >>= 1) s += __shfl_xor(s, off);

    if (lane == 0)
        atomicAdd(out, (m + __logf(s) - row[Y]) * (1.0f / (B_ * T_)));
}

// ---------------- launch ----------------
extern "C" void kernel_launch(void* const* d_in, const int* in_sizes, int n_in,
                              void* d_out, int out_size, void* d_ws, size_t ws_size,
                              hipStream_t stream) {
    const float* hn  = (const float*)d_in[0];
    const float* dec = (const float*)d_in[1];
    const float* W1  = (const float*)d_in[2];
    const float* W2  = (const float*)d_in[3];
    const float* V   = (const float*)d_in[4];
    const int*   Xi  = (const int*)d_in[5];
    const int*   Yi  = (const int*)d_in[6];
    float* out = (float*)d_out;

    char* ws = (char*)d_ws;
    size_t off = 0;
    auto alloc = [&](size_t bytes) -> char* {
        char* p = ws + off;
        off += (bytes + 255) & ~(size_t)255;
        return p;
    };
    __bf16* web    = (__bf16*)alloc((size_t)B_ * L_ * H_ * 2);
    float*  wdf    = (float*)alloc((size_t)B_ * T_ * H_ * 4);
    float*  scores = (float*)alloc((size_t)B_ * T_ * L_ * 4);
    __bf16* allb   = (__bf16*)alloc((size_t)ALLELEM * 2);

    prep_k<<<ALLELEM / (256 * 8), 256, 0, stream>>>(hn, dec, W1, W2, Yi, allb, out);
    gemm_k<<<396, 256, 0, stream>>>(allb, web, wdf);
    scores_k<<<dim3(B_, L_ / 16, 2), 256, 0, stream>>>(web, wdf, V, Xi, scores);
    loss_k<<<B_ * T_, 64, 0, stream>>>(scores, Xi, Yi, out);
}

// Round 11
// 142.080 us; speedup vs baseline: 1.2442x; 1.0216x over previous
//
#include <hip/hip_runtime.h>
#include <hip/hip_bf16.h>
#include <math.h>

#define SELU_SCALE 1.0507009873554805f
#define SELU_ALPHA 1.6732632423543772f

static constexpr int B_ = 16, T_ = 16, L_ = 512, H_ = 768;
static constexpr int WSZ = 768 * 768;          // one weight matrix, elements
static constexpr int HNELEM = B_ * L_ * H_;    // 6291456
static constexpr int DJELEM = B_ * T_ * H_;    // 196608
// combined bf16 staging buffer layout: [hn | W1 | W2 | dj-gather]
static constexpr int ALLELEM = HNELEM + 2 * WSZ + DJELEM;   // 7667712 (/2048 = 3744)

typedef __bf16 bf16x8 __attribute__((ext_vector_type(8)));
typedef float  f32x4  __attribute__((ext_vector_type(4)));

__device__ __forceinline__ float bf_lo(unsigned u) { return __uint_as_float(u << 16); }
__device__ __forceinline__ float bf_hi(unsigned u) { return __uint_as_float(u & 0xFFFF0000u); }

__device__ __forceinline__ float selu_core(float x) {
    float e = fmaf(__expf(x), SELU_ALPHA, -SELU_ALPHA);
    return x > 0.0f ? x : e;
}

// LDS k-segment slot swizzle: slot = seg ^ ((row>>1)&3). Measured 0 conflicts
// for these write/read patterns. Note xsw(r+16) == xsw(r), so fragment offsets
// are affine in the 16-row fragment index.
__device__ __forceinline__ int xsw(int r) { return (r >> 1) & 3; }

__device__ __forceinline__ bf16x8 pack8(float4 a, float4 b) {
    bf16x8 o;
    o[0] = (__bf16)a.x; o[1] = (__bf16)a.y; o[2] = (__bf16)a.z; o[3] = (__bf16)a.w;
    o[4] = (__bf16)b.x; o[5] = (__bf16)b.y; o[6] = (__bf16)b.z; o[7] = (__bf16)b.w;
    return o;
}

// ---------------- prep: {hn, W1, W2, dec-gather} -> bf16 (one pass, ~7us) -------
// r3/r4-proven bit-identical (same RTN rounding as the old in-register staging).
// Enables gemm_k's global_load_lds DMA staging. Also zeroes the loss accumulator.
__global__ __launch_bounds__(256) void prep_k(
        const float* __restrict__ hn, const float* __restrict__ dec,
        const float* __restrict__ w1, const float* __restrict__ w2,
        const int* __restrict__ Yi,
        __bf16* __restrict__ allb, float* __restrict__ out) {
    if (blockIdx.x == 0 && threadIdx.x == 0) out[0] = 0.0f;
    int idx = (blockIdx.x * 256 + threadIdx.x) * 8;
    const float* src;
    if (idx < HNELEM) {
        src = hn + idx;
    } else if (idx < HNELEM + WSZ) {
        src = w1 + (idx - HNELEM);
    } else if (idx < HNELEM + 2 * WSZ) {
        src = w2 + (idx - HNELEM - WSZ);
    } else {
        int e = idx - (HNELEM + 2 * WSZ);      // < 196608
        int r = e / 768, c = e - r * 768;      // r = bt, 8 elems stay in-row
        src = dec + ((size_t)((r >> 4) * L_ + Yi[r])) * H_ + c;
    }
    float4 a = *(const float4*)src;
    float4 b = *(const float4*)(src + 4);
    *(bf16x8*)(allb + idx) = pack8(a, b);
}

// ---------------- fused NT GEMM: global_load_lds + counted-vmcnt 3-buffer -------
// r10-verified (absmax 0, gemm below the 42us fill threshold). 3 LDS buffers,
// prefetch distance 2, s_waitcnt vmcnt(4) steady-state (never 0): the newest
// stage's 4 DMA loads stay in flight across the barrier; in-order vm retirement
// guarantees the oldest stage landed. Final tile peeled with vmcnt(0) (the r9
// tail race: only 4 ops outstanding there, vmcnt(4) wouldn't wait). Race audit:
// STAGE(t+2) issues AFTER barrier(t); buf[(t+2)%3] was last read at iter t-1,
// sealed by that barrier. sched_barrier(0) pins COMPUTE's ds_reads below the
// sync. 128x128 tile, BK=32, 48KB LDS, 4 waves of 64x64, pre-swizzled DMA
// source (xsw; LDS linear per m104/m173), measured-0-conflict fragment reads.
__global__ __launch_bounds__(256, 2) void gemm_k(
        const __bf16* __restrict__ allb,
        __bf16* __restrict__ web, float* __restrict__ wdf) {
    __shared__ __bf16 sm[3][2][4096];   // [buf][A/B][128*32] = 48 KB

    int bx = blockIdx.x;
    const __bf16 *Ab, *Bb; int m0, n0; bool wd;
    if (bx < 384) {                      // WE: 64 m-tiles x 6 n-chunks
        wd = false; Ab = allb; Bb = allb + HNELEM;
        m0 = (bx & 63) * 128; n0 = (bx >> 6) * 128;
    } else {                             // WD: 2 m-tiles x 6 n-chunks
        wd = true; bx -= 384;
        Ab = allb + HNELEM + 2 * WSZ; Bb = allb + HNELEM + WSZ;
        m0 = (bx & 1) * 128;  n0 = (bx >> 1) * 128;
    }

    const int tid = threadIdx.x, wave = tid >> 6, lane = tid & 63;
    const int wm = (wave >> 1) * 64, wn = (wave & 1) * 64;
    const int lr = lane & 15, q = lane >> 4;
    const int l4 = lane >> 2, sl = lane & 3;

    // staging rows: instr0 -> rows wave*16 + l4 (0..63), instr1 -> +64.
    // lane's 16B lands at ldsBase + lane*16 (linear); pre-swizzled global seg.
    const int ar0 = wave * 16 + l4, ar1 = ar0 + 64;
    const __bf16* gA0 = Ab + (size_t)(m0 + ar0) * 768 + (sl ^ xsw(ar0)) * 8;
    const __bf16* gA1 = Ab + (size_t)(m0 + ar1) * 768 + (sl ^ xsw(ar1)) * 8;
    const __bf16* gB0 = Bb + (size_t)(n0 + ar0) * 768 + (sl ^ xsw(ar0)) * 8;
    const __bf16* gB1 = Bb + (size_t)(n0 + ar1) * 768 + (sl ^ xsw(ar1)) * 8;
    const int ld0 = wave * 512;          // element offset of this wave's 1KB slice
    const int ld1 = 2048 + wave * 512;

    // fragment base offsets (xsw(r+16)==xsw(r) -> affine in fragment index)
    const int aoff0 = (wm + lr) * 32 + (q ^ xsw(wm + lr)) * 8;
    const int boff0 = (wn + lr) * 32 + (q ^ xsw(wn + lr)) * 8;

    f32x4 acc[4][4] = {};

#define STAGE(b, kk)                                                                        \
    {                                                                                       \
        __builtin_amdgcn_global_load_lds((const __attribute__((address_space(1))) void*)(gA0 + (kk)), \
            (__attribute__((address_space(3))) void*)&sm[b][0][ld0], 16, 0, 0);             \
        __builtin_amdgcn_global_load_lds((const __attribute__((address_space(1))) void*)(gA1 + (kk)), \
            (__attribute__((address_space(3))) void*)&sm[b][0][ld1], 16, 0, 0);             \
        __builtin_amdgcn_global_load_lds((const __attribute__((address_space(1))) void*)(gB0 + (kk)), \
            (__attribute__((address_space(3))) void*)&sm[b][1][ld0], 16, 0, 0);             \
        __builtin_amdgcn_global_load_lds((const __attribute__((address_space(1))) void*)(gB1 + (kk)), \
            (__attribute__((address_space(3))) void*)&sm[b][1][ld1], 16, 0, 0);             \
    }

#define COMPUTE(b)                                                                          \
    {                                                                                       \
        bf16x8 af[4], bfr[4];                                                               \
        _Pragma("unroll")                                                                   \
        for (int i = 0; i < 4; ++i) af[i]  = *(const bf16x8*)&sm[b][0][aoff0 + i * 512];    \
        _Pragma("unroll")                                                                   \
        for (int j = 0; j < 4; ++j) bfr[j] = *(const bf16x8*)&sm[b][1][boff0 + j * 512];    \
        _Pragma("unroll")                                                                   \
        for (int i = 0; i < 4; ++i)                                                         \
            _Pragma("unroll")                                                               \
            for (int j = 0; j < 4; ++j)                                                     \
                acc[i][j] = __builtin_amdgcn_mfma_f32_16x16x32_bf16(af[i], bfr[j], acc[i][j], 0, 0, 0); \
    }

// one steady-state k-step: wait until the oldest in-flight stage landed
// (<=4 outstanding, in-order retirement), barrier, prefetch tile tt+2, compute
// tile tt. Valid for tt <= 22 (two stages in flight at the wait).
#define ITER(tt, bc, bs)                                                                    \
    {                                                                                       \
        asm volatile("s_waitcnt vmcnt(4)" ::: "memory");                                    \
        __builtin_amdgcn_s_barrier();                                                       \
        __builtin_amdgcn_sched_barrier(0);                                                  \
        if ((tt) + 2 < 24) STAGE(bs, ((tt) + 2) * 32)                                       \
        COMPUTE(bc)                                                                         \
    }

    // prologue: stage tiles 0 and 1 (no drain -- ITER's vmcnt(4) covers it)
    STAGE(0, 0)
    STAGE(1, 32)

#pragma unroll 1
    for (int g = 0; g < 7; ++g) {       // tiles 0..20
        const int t0g = g * 3;
        ITER(t0g + 0, 0, 2)
        ITER(t0g + 1, 1, 0)
        ITER(t0g + 2, 2, 1)
    }
    ITER(21, 0, 2)                      // stages tile 23 into buf 2
    ITER(22, 1, 0)                      // stages nothing
    // FINAL tile 23: only 4 ops outstanding here -- vmcnt(4) would NOT wait.
    // Drain fully, then one barrier so all waves' DMA is visible.
    asm volatile("s_waitcnt vmcnt(0)" ::: "memory");
    __builtin_amdgcn_s_barrier();
    __builtin_amdgcn_sched_barrier(0);
    COMPUTE(2)
#undef ITER
#undef STAGE
#undef COMPUTE

#pragma unroll
    for (int i = 0; i < 4; ++i)
#pragma unroll
        for (int j = 0; j < 4; ++j)
#pragma unroll
            for (int r = 0; r < 4; ++r) {
                int row = m0 + wm + i * 16 + q * 4 + r;
                int col = n0 + wn + j * 16 + lr;
                if (!wd) web[(size_t)row * 768 + col] = (__bf16)acc[i][j][r];
                else     wdf[(size_t)row * 768 + col] = acc[i][j][r];
            }
}

// ---------------- scores: LDS-free, register-cached, z-split 4 for occupancy ----
// Block = (b, 16 l rows, 4 t's). 256 thr = 16 ls x 16 hc. Thread owns the 48
// h-elements {hc*8 + j*128 + e}, keeps we (unpacked bf16) and V in registers,
// streams wd[t] (f32, L2-resident) per t. r10 counters: VGPR=64 -> HW allows
// 8 waves/SIMD, but 1024 blocks supplied only 4/SIMD to an L2-LATENCY-BOUND
// loop (12 dependent loads/t). Grid now 16x32x4 = 2048 blocks = 8 blocks/CU
// = 32 waves/CU = 100% static occupancy; TLP doubles. Cost: we/vv fills 4x
// instead of 2x (~+1.5us L2 traffic, overlapped). Xindex monotone in t ->
// valid t's form a PREFIX per wave: tend computed once, loop branch-free,
// fully-masked waves exit BEFORE the 24 we/vv loads. unroll 2 interleaves two
// t-chains. lb(256,4) keeps we/vv hoisted (r2: no-hint sank them into the loop).
__global__ __launch_bounds__(256, 4) void scores_k(
        const __bf16* __restrict__ web, const float* __restrict__ wdf,
        const float* __restrict__ V, const int* __restrict__ Xi,
        float* __restrict__ scores) {
    const int b  = blockIdx.x;
    const int l0 = ((int)gridDim.y - 1 - (int)blockIdx.y) * 16;   // heavy first
    const int t0 = blockIdx.z * 4;
    const int tid = threadIdx.x;
    const int ls = tid >> 4, hc = tid & 15;
    const int l  = l0 + ls;
    const int h0 = hc * 8;
    const int bT = b * T_;

    const int wmaxl = l0 + ((tid >> 6) << 2) + 3;   // wave covers ls = 4w..4w+3
    if (wmaxl < Xi[bT + t0]) return;                // whole window masked (prefix)
    int tend = t0;
#pragma unroll
    for (int tt = t0; tt < t0 + 4; ++tt)
        if (wmaxl >= Xi[bT + tt]) tend = tt + 1;    // valid t's are a prefix

    float we[48], vv[48];
    const __bf16* wr = web + ((size_t)(b * L_ + l)) * H_ + h0;
#pragma unroll
    for (int j = 0; j < 6; ++j) {
        uint4 u = *(const uint4*)(wr + j * 128);
        we[j*8+0] = bf_lo(u.x); we[j*8+1] = bf_hi(u.x);
        we[j*8+2] = bf_lo(u.y); we[j*8+3] = bf_hi(u.y);
        we[j*8+4] = bf_lo(u.z); we[j*8+5] = bf_hi(u.z);
        we[j*8+6] = bf_lo(u.w); we[j*8+7] = bf_hi(u.w);
    }
    const float* vp = V + h0;
#pragma unroll
    for (int j = 0; j < 6; ++j) {
        float4 a = *(const float4*)(vp + j * 128);
        float4 c = *(const float4*)(vp + j * 128 + 4);
        vv[j*8+0] = a.x; vv[j*8+1] = a.y; vv[j*8+2] = a.z; vv[j*8+3] = a.w;
        vv[j*8+4] = c.x; vv[j*8+5] = c.y; vv[j*8+6] = c.z; vv[j*8+7] = c.w;
    }

#pragma unroll 2
    for (int t = t0; t < tend; ++t) {
        const float* wdp = wdf + ((size_t)(bT + t)) * H_ + h0;
        float a0 = 0.f, a1 = 0.f, a2 = 0.f, a3 = 0.f;
#pragma unroll
        for (int j = 0; j < 6; ++j) {
            float4 x = *(const float4*)(wdp + j * 128);
            float4 y = *(const float4*)(wdp + j * 128 + 4);
            a0 = fmaf(selu_core(we[j*8+0] + x.x), vv[j*8+0], a0);
            a1 = fmaf(selu_core(we[j*8+1] + x.y), vv[j*8+1], a1);
            a2 = fmaf(selu_core(we[j*8+2] + x.z), vv[j*8+2], a2);
            a3 = fmaf(selu_core(we[j*8+3] + x.w), vv[j*8+3], a3);
            a0 = fmaf(selu_core(we[j*8+4] + y.x), vv[j*8+4], a0);
            a1 = fmaf(selu_core(we[j*8+5] + y.y), vv[j*8+5], a1);
            a2 = fmaf(selu_core(we[j*8+6] + y.z), vv[j*8+6], a2);
            a3 = fmaf(selu_core(we[j*8+7] + y.w), vv[j*8+7], a3);
        }
        float dot = (a0 + a1) + (a2 + a3);
        dot += __shfl_xor(dot, 1);
        dot += __shfl_xor(dot, 2);
        dot += __shfl_xor(dot, 4);
        dot += __shfl_xor(dot, 8);
        if (hc == 0) {
            dot *= SELU_SCALE;
            float sc = dot > 0.0f ? SELU_SCALE * dot
                                  : SELU_SCALE * SELU_ALPHA * (__expf(dot) - 1.0f);
            scores[((size_t)(bT + t)) * L_ + l] = sc;
        }
    }
}

// ---------------- per-(b,t) masked logsumexp + gold + mean (atomic) -------------
__global__ __launch_bounds__(64) void loss_k(
        const float* __restrict__ scores, const int* __restrict__ Xi,
        const int* __restrict__ Yi, float* __restrict__ out) {
    const int bt = blockIdx.x;
    const int lane = threadIdx.x;
    const int X = Xi[bt];
    const int Y = Yi[bt];
    const float* row = scores + (size_t)bt * L_;

    float m = -INFINITY;
    for (int l = X + lane; l < L_; l += 64) m = fmaxf(m, row[l]);
#pragma unroll
    for (int off = 32; off > 0; off >>= 1) m = fmaxf(m, __shfl_xor(m, off));

    float s = 0.0f;
    for (int l = X + lane; l < L_; l += 64) s += __expf(row[l] - m);
#pragma unroll
    for (int off = 32; off > 0; off >>= 1) s += __shfl_xor(s, off);

    if (lane == 0)
        atomicAdd(out, (m + __logf(s) - row[Y]) * (1.0f / (B_ * T_)));
}

// ---------------- launch ----------------
extern "C" void kernel_launch(void* const* d_in, const int* in_sizes, int n_in,
                              void* d_out, int out_size, void* d_ws, size_t ws_size,
                              hipStream_t stream) {
    const float* hn  = (const float*)d_in[0];
    const float* dec = (const float*)d_in[1];
    const float* W1  = (const float*)d_in[2];
    const float* W2  = (const float*)d_in[3];
    const float* V   = (const float*)d_in[4];
    const int*   Xi  = (const int*)d_in[5];
    const int*   Yi  = (const int*)d_in[6];
    float* out = (float*)d_out;

    char* ws = (char*)d_ws;
    size_t off = 0;
    auto alloc = [&](size_t bytes) -> char* {
        char* p = ws + off;
        off += (bytes + 255) & ~(size_t)255;
        return p;
    };
    __bf16* web    = (__bf16*)alloc((size_t)B_ * L_ * H_ * 2);
    float*  wdf    = (float*)alloc((size_t)B_ * T_ * H_ * 4);
    float*  scores = (float*)alloc((size_t)B_ * T_ * L_ * 4);
    __bf16* allb   = (__bf16*)alloc((size_t)ALLELEM * 2);

    prep_k<<<ALLELEM / (256 * 8), 256, 0, stream>>>(hn, dec, W1, W2, Yi, allb, out);
    gemm_k<<<396, 256, 0, stream>>>(allb, web, wdf);
    scores_k<<<dim3(B_, L_ / 16, 4), 256, 0, stream>>>(web, wdf, V, Xi, scores);
    loss_k<<<B_ * T_, 64, 0, stream>>>(scores, Xi, Yi, out);
}